// Round 11
// baseline (745.831 us; speedup 1.0000x reference)
//
#include <hip/hip_runtime.h>
#include <hip/hip_bf16.h>

// Problem constants (fixed shapes)
#define NN 2048      // nodes
#define EE 65536     // edges
#define NF_ 128
#define HH 512
#define NHH 8
#define HD 64
#define DEPTH 5
#define KSPLIT 3
#define NTILE_TOT (NN / 64)      // 32
#define LOG2E 1.4426950408889634f
#define QSCALE 0.18033688011112042f   // 0.125 * log2e, folded into Q at projection

typedef __attribute__((ext_vector_type(8))) short bf16x8;
typedef __attribute__((ext_vector_type(4))) float f32x4;

__device__ __forceinline__ ushort f2bf(float x) {
    uint u = __builtin_bit_cast(uint, x);
    u += 0x7fffu + ((u >> 16) & 1u);
    return (ushort)(u >> 16);
}

#define GLD16(gp, lp)                                                          \
    __builtin_amdgcn_global_load_lds(                                          \
        (const __attribute__((address_space(1))) unsigned int*)(gp),           \
        (__attribute__((address_space(3))) unsigned int*)(lp), 16, 0, 0)

// ---------------- bf16 MFMA GEMM: C = A[M,K] @ Bt[N,K]^T + bias
// OUT: 0 = f32 C; 1 = f32 C + bf16 Cb; 2 = bf16 Cb; 3 = qkv scatter (Q pre-scaled by QSCALE)
template<int BM, int BN, int OUT, int RELU>
__global__ __launch_bounds__(256) void gemm_mfma(const ushort* __restrict__ A,
                                                 const ushort* __restrict__ Bt,
                                                 const float* __restrict__ bias,
                                                 float* __restrict__ C,
                                                 ushort* __restrict__ Cb,
                                                 ushort* __restrict__ qb,
                                                 ushort* __restrict__ kb,
                                                 ushort* __restrict__ vtb,
                                                 int M, int N, int K) {
    constexpr int WM = BM / 2, WN = BN / 2;
    constexpr int MR = BM / 32, NR = BN / 32;
    __shared__ __align__(16) ushort As[2][BM * 64];
    __shared__ __align__(16) ushort Bs[2][BN * 64];
    const int t = threadIdx.x;
    const int w = t >> 6, l = t & 63;
    const int wr = w >> 1, wc = w & 1;
    const int m0 = blockIdx.y * BM, n0 = blockIdx.x * BN;

    f32x4 acc[MR][NR];
#pragma unroll
    for (int m = 0; m < MR; ++m)
#pragma unroll
        for (int n = 0; n < NR; ++n) acc[m][n] = (f32x4){0.f, 0.f, 0.f, 0.f};

    const int srow = t >> 3, sch = t & 7;
    auto stage = [&](int buf, int kt) {
#pragma unroll
        for (int r = 0; r < MR; ++r) {
            int rr = r * 32 + srow;
            int c = sch ^ (rr & 7);                   // inverse swizzle on SOURCE
            GLD16(A + (size_t)(m0 + rr) * K + kt * 64 + c * 8,
                  &As[buf][rr * 64 + sch * 8]);       // linear LDS dest
        }
#pragma unroll
        for (int r = 0; r < NR; ++r) {
            int rr = r * 32 + srow;
            int c = sch ^ (rr & 7);
            GLD16(Bt + (size_t)(n0 + rr) * K + kt * 64 + c * 8,
                  &Bs[buf][rr * 64 + sch * 8]);
        }
    };

    stage(0, 0);
    const int NT = K / 64;
    for (int kt = 0; kt < NT; ++kt) {
        __syncthreads();
        if (kt + 1 < NT) stage((kt + 1) & 1, kt + 1);
        const int buf = kt & 1;
#pragma unroll
        for (int kk = 0; kk < 2; ++kk) {
            bf16x8 af[MR], bfr[NR];
#pragma unroll
            for (int m = 0; m < MR; ++m) {
                int R = wr * WM + m * 16 + (l & 15);
                int c = kk * 4 + (l >> 4);
                af[m] = *(const bf16x8*)&As[buf][R * 64 + (c ^ (R & 7)) * 8];  // swizzled read
            }
#pragma unroll
            for (int n = 0; n < NR; ++n) {
                int R = wc * WN + n * 16 + (l & 15);
                int c = kk * 4 + (l >> 4);
                bfr[n] = *(const bf16x8*)&Bs[buf][R * 64 + (c ^ (R & 7)) * 8];
            }
#pragma unroll
            for (int m = 0; m < MR; ++m)
#pragma unroll
                for (int n = 0; n < NR; ++n)
                    acc[m][n] = __builtin_amdgcn_mfma_f32_16x16x32_bf16(af[m], bfr[n], acc[m][n], 0, 0, 0);
        }
    }

    // epilogue: C/D layout col=l&15, row=(l>>4)*4+j
#pragma unroll
    for (int m = 0; m < MR; ++m) {
        int row = m0 + wr * WM + m * 16 + (l >> 4) * 4;
#pragma unroll
        for (int n = 0; n < NR; ++n) {
            int col = n0 + wc * WN + n * 16 + (l & 15);
            float bv = bias[col];
#pragma unroll
            for (int j = 0; j < 4; ++j) {
                float vv = acc[m][n][j] + bv;
                if (RELU) vv = fmaxf(vv, 0.f);
                int r = row + j;
                if (OUT == 0) {
                    C[(size_t)r * N + col] = vv;
                } else if (OUT == 1) {
                    C[(size_t)r * N + col] = vv;
                    Cb[(size_t)r * N + col] = f2bf(vv);
                } else if (OUT == 2) {
                    Cb[(size_t)r * N + col] = f2bf(vv);
                } else {
                    int type = col >> 9, head = (col >> 6) & 7, dd = col & 63;
                    if (type == 0) qb[((size_t)head * NN + r) * 64 + dd] = f2bf(vv * QSCALE);
                    else if (type == 1) kb[((size_t)head * NN + r) * 64 + dd] = f2bf(vv);
                    else vtb[((size_t)head * 64 + dd) * NN + r] = f2bf(vv);
                }
            }
        }
    }
}

// ---------------- setup converts
__global__ __launch_bounds__(256) void xcvt(const float* __restrict__ x, ushort* __restrict__ xb, int n) {
    int i = blockIdx.x * 256 + threadIdx.x;
    if (i < n) xb[i] = f2bf(x[i]);
}

__global__ __launch_bounds__(256) void wtrans(const float* __restrict__ W, ushort* __restrict__ WT,
                                              int K, int N, int rowoff) {
    __shared__ float tile[32][33];
    int n0 = blockIdx.x * 32, k0 = blockIdx.y * 32;
    int tc = threadIdx.x & 31, tr = threadIdx.x >> 5;
#pragma unroll
    for (int i = 0; i < 32; i += 8) tile[tr + i][tc] = W[(size_t)(k0 + tr + i) * N + n0 + tc];
    __syncthreads();
#pragma unroll
    for (int i = 0; i < 32; i += 8)
        WT[(size_t)(rowoff + n0 + tr + i) * K + k0 + tc] = f2bf(tile[tc][tr + i]);
}

__global__ __launch_bounds__(256) void bconcat(const float* __restrict__ a, const float* __restrict__ b,
                                               const float* __restrict__ c, float* __restrict__ o) {
    int i = blockIdx.x * 256 + threadIdx.x;
    if (i < 1536) o[i] = i < 512 ? a[i] : (i < 1024 ? b[i - 512] : c[i - 1024]);
}

// ---------------- e_bias = edge_attr @ We + be
__global__ __launch_bounds__(256) void ebias_kernel(const float* __restrict__ ea,
                                                    const float* __restrict__ We,
                                                    const float* __restrict__ be,
                                                    float* __restrict__ eb) {
    int e = blockIdx.x * 256 + threadIdx.x;
    float a[16];
#pragma unroll
    for (int i = 0; i < 16; ++i) a[i] = ea[(size_t)e * 16 + i];
#pragma unroll
    for (int j = 0; j < 8; ++j) {
        float s = be[j];
#pragma unroll
        for (int i = 0; i < 16; ++i) s += a[i] * We[i * 8 + j];
        eb[(size_t)e * 8 + j] = s;
    }
}

// ---------------- dedupe: last edge index wins per (src,dst)
__global__ __launch_bounds__(256) void amax_kernel(const int* __restrict__ eidx, int* __restrict__ lastE) {
    int e = blockIdx.x * 256 + threadIdx.x;
    int s = eidx[e], d = eidx[EE + e];
    atomicMax(&lastE[s * NN + d], e);
}

__global__ __launch_bounds__(256) void count_kernel(const int* __restrict__ eidx,
                                                    const int* __restrict__ lastE,
                                                    int* __restrict__ cnt) {
    int e = blockIdx.x * 256 + threadIdx.x;
    int s = eidx[e], d = eidx[EE + e];
    if (lastE[s * NN + d] == e) atomicAdd(&cnt[s], 1);
}

__global__ __launch_bounds__(256) void scan2048(const int* __restrict__ cnt,
                                                int* __restrict__ rowptr) {
    __shared__ int sums[256];
    int t = threadIdx.x;
    int loc[8];
    int s = 0;
#pragma unroll
    for (int i = 0; i < 8; ++i) { loc[i] = s; s += cnt[t * 8 + i]; }
    sums[t] = s;
    __syncthreads();
    for (int off = 1; off < 256; off <<= 1) {
        int v = (t >= off) ? sums[t - off] : 0;
        __syncthreads();
        sums[t] += v;
        __syncthreads();
    }
    int base = (t == 0) ? 0 : sums[t - 1];
#pragma unroll
    for (int i = 0; i < 8; ++i) rowptr[t * 8 + i] = base + loc[i];
    if (t == 255) rowptr[NN] = sums[255];
}

// ---------------- (row, key-tile) bucketing of bias entries (layer-invariant)
__global__ __launch_bounds__(256) void rt_count(const int* __restrict__ eidx,
                                                const int* __restrict__ lastE,
                                                int* __restrict__ cnt2) {
    int e = blockIdx.x * 256 + threadIdx.x;
    int s = eidx[e], d = eidx[EE + e];
    if (lastE[s * NN + d] == e) atomicAdd(&cnt2[s * NTILE_TOT + (d >> 6)], 1);
}

__global__ __launch_bounds__(256) void rt_scan(const int* __restrict__ rowptr,
                                               const int* __restrict__ cnt2,
                                               int* __restrict__ rtptr,
                                               int* __restrict__ rtoff) {
    int row = blockIdx.x * 256 + threadIdx.x;
    if (row >= NN) return;
    int base = rowptr[row];
#pragma unroll
    for (int t = 0; t < NTILE_TOT; ++t) {
        rtptr[row * NTILE_TOT + t] = base;
        rtoff[row * NTILE_TOT + t] = base;
        base += cnt2[row * NTILE_TOT + t];
    }
    if (row == NN - 1) rtptr[NN * NTILE_TOT] = base;
}

// fill buckets: dst stored relative to tile (0..63); bias pre-scaled by log2e
__global__ __launch_bounds__(256) void rt_fill(const int* __restrict__ eidx,
                                               const int* __restrict__ lastE,
                                               const float* __restrict__ eb,
                                               int* __restrict__ rtoff,
                                               int* __restrict__ csr_dst,
                                               float* __restrict__ csr_b) {
    int e = blockIdx.x * 256 + threadIdx.x;
    int s = eidx[e], d = eidx[EE + e];
    if (lastE[s * NN + d] == e) {
        int pos = atomicAdd(&rtoff[s * NTILE_TOT + (d >> 6)], 1);
        csr_dst[pos] = d & 63;
#pragma unroll
        for (int j = 0; j < 8; ++j) csr_b[(size_t)pos * 8 + j] = eb[(size_t)e * 8 + j] * LOG2E;
    }
}

// ---------------- split-K flash attention, wave-autonomous, BARRIER-FREE main loop
// K/V fragments loaded global->register (L2-resident), 1-tile prefetch; no LDS K/V,
// no global_load_lds, no __syncthreads in loop. grid 768 = qblk(32) x head(8) x ks(3).
// BIASLDS=1: bias via per-wave LDS mini-tile; BIASLDS=0: in-register predicated adds.
template<int BIASLDS>
__global__ __launch_bounds__(256, 3) void attn_mfma(const ushort* __restrict__ qb,
                                                    const ushort* __restrict__ kb,
                                                    const ushort* __restrict__ vtb,
                                                    const int* __restrict__ rtptr,
                                                    const int* __restrict__ csr_dst,
                                                    const float* __restrict__ csr_b,
                                                    float* __restrict__ opart,
                                                    float* __restrict__ Mp,
                                                    float* __restrict__ Sp) {
    const int id = blockIdx.x;
    const int f = (id & 7) * 96 + (id >> 3);    // 768 blocks, 96/XCD
    const int n0 = (f & 31) * 64;
    const int head = (f >> 5) & 7;
    const int ks = f >> 8;                       // 0..2
    const int tstart = (ks * 32) / 3, tend = ((ks + 1) * 32) / 3;   // 10/11/11 tiles
    const int t = threadIdx.x;
    const int w = t >> 6, l = t & 63;
    const int lq = l & 15, lg = l >> 4;

    __shared__ __align__(16) ushort Bb[4][16 * 72];    // per-wave bias mini-tile (bf16)
    __shared__ int Rt[64][12];                         // bucket bounds per block row

    // persistent Q fragments (pre-scaled by QSCALE): rows n0 + w*16 + lq
    bf16x8 qf0, qf1;
    {
        int r = n0 + w * 16 + lq;
        const ushort* qp = qb + ((size_t)head * NN + r) * HD + lg * 8;
        qf0 = *(const bf16x8*)qp;
        qf1 = *(const bf16x8*)(qp + 32);
    }
    const int ntile = tend - tstart;
    for (int i = t; i < 64 * 12; i += 256) {
        int r = i / 12, c = i % 12;
        if (c <= ntile) Rt[r][c] = rtptr[(n0 + r) * NTILE_TOT + tstart + c];
    }
    __syncthreads();   // Rt visible (only barrier in kernel)

    float M = -1e30f, S = 0.f;
    f32x4 o[4];
#pragma unroll
    for (int db = 0; db < 4; ++db) o[db] = (f32x4){0.f, 0.f, 0.f, 0.f};

    // per-lane K/V fragment registers (single-buffered; prefetched 1 tile ahead)
    bf16x8 kf0[4], kf1[4], vf0[4], vf1[4];
    const ushort* kbase0 = kb + ((size_t)head * NN) * 64;       // + tile*4096 + (b*16+lq)*64 + lg*8
    const ushort* vbase0 = vtb + (size_t)head * 64 * NN;        // + (db*16+lq)*NN + tile*64 + lg*8
    auto loadK = [&](int tile) {
        const ushort* p = kbase0 + (size_t)tile * 4096 + lq * 64 + lg * 8;
#pragma unroll
        for (int b = 0; b < 4; ++b) {
            kf0[b] = *(const bf16x8*)(p);
            kf1[b] = *(const bf16x8*)(p + 32);
            p += 1024;   // next 16 key rows
        }
    };
    auto loadV = [&](int tile) {
        const ushort* p = vbase0 + (size_t)lq * NN + tile * 64 + lg * 8;
#pragma unroll
        for (int db = 0; db < 4; ++db) {
            vf0[db] = *(const bf16x8*)(p);
            vf1[db] = *(const bf16x8*)(p + 32);
            p += (size_t)16 * NN;   // next 16 dim rows
        }
    };
    loadK(tstart);
    loadV(tstart);

    // P lane-exchange constants (dest lane lg pulls from src lane ((2lg+c)&3)*16+lq)
    const int sl0 = (((lg << 1) + 0) & 3) * 16 + lq;
    const int sl1 = (((lg << 1) + 1) & 3) * 16 + lq;
    const int hi = lg & 2;

    for (int tt = tstart; tt < tend; ++tt) {
        const int tl = tt - tstart;
        const int rq = w * 16 + lq;
        const int p0 = Rt[rq][tl], p1 = Rt[rq][tl + 1];

        if (BIASLDS) {
            // zero this wave's mini-tile (wave-coherent, no barrier needed)
            for (int i = l; i < 144; i += 64)
                *(uint4*)&Bb[w][i * 8] = (uint4){0, 0, 0, 0};
            // scatter bucket entries (lg==0 lanes only; ~1 entry/row avg)
            if (lg == 0) {
                for (int e = p0; e < p1; ++e)
                    Bb[w][lq * 72 + csr_dst[e]] = f2bf(csr_b[(size_t)e * 8 + head]);
            }
        }

        // ---- QK^T (swapped): vv[b][j] = score[q=lq][key = b*16 + lg*4 + j]
        f32x4 vv[4];
        {
            __builtin_amdgcn_s_setprio(1);
#pragma unroll
            for (int b = 0; b < 4; ++b) {
                f32x4 s_ = {0.f, 0.f, 0.f, 0.f};
                s_ = __builtin_amdgcn_mfma_f32_16x16x32_bf16(kf0[b], qf0, s_, 0, 0, 0);
                s_ = __builtin_amdgcn_mfma_f32_16x16x32_bf16(kf1[b], qf1, s_, 0, 0, 0);
                vv[b] = s_;
            }
            __builtin_amdgcn_s_setprio(0);
        }
        // prefetch next K tile into registers (hidden under softmax+PV)
        if (tt + 1 < tend) loadK(tt + 1);

        // ---- bias merge
        if (BIASLDS) {
#pragma unroll
            for (int b = 0; b < 4; ++b) {
                uint2 bb = *(const uint2*)&Bb[w][lq * 72 + b * 16 + lg * 4];
                vv[b][0] += __builtin_bit_cast(float, bb.x << 16);
                vv[b][1] += __builtin_bit_cast(float, bb.x & 0xffff0000u);
                vv[b][2] += __builtin_bit_cast(float, bb.y << 16);
                vv[b][3] += __builtin_bit_cast(float, bb.y & 0xffff0000u);
            }
        } else {
            for (int e = p0; e < p1; ++e) {
                int dd = csr_dst[e];                 // 0..63
                if (((dd >> 2) & 3) == lg) {
                    float bv = csr_b[(size_t)e * 8 + head];
#pragma unroll
                    for (int b = 0; b < 4; ++b)
#pragma unroll
                        for (int j = 0; j < 4; ++j)
                            vv[b][j] += (b == (dd >> 4) && j == (dd & 3)) ? bv : 0.f;
                }
            }
        }

        // ---- wave-local online softmax (log2 space), exact defer-rescale
        float mx = vv[0][0];
#pragma unroll
        for (int b = 0; b < 4; ++b)
#pragma unroll
            for (int j = 0; j < 4; ++j) mx = fmaxf(mx, vv[b][j]);
        mx = fmaxf(mx, __shfl_xor(mx, 16, 64));
        mx = fmaxf(mx, __shfl_xor(mx, 32, 64));
        if (!__all(mx <= M)) {
            float Mn = fmaxf(M, mx);
            float fr = exp2f(M - Mn);
            M = Mn;
            S *= fr;
#pragma unroll
            for (int j = 0; j < 4; ++j) {
                float Fj = __shfl(fr, lg * 4 + j, 64);
                o[0][j] *= Fj; o[1][j] *= Fj; o[2][j] *= Fj; o[3][j] *= Fj;
            }
        }
        float ts = 0.f;
#pragma unroll
        for (int b = 0; b < 4; ++b)
#pragma unroll
            for (int j = 0; j < 4; ++j) { vv[b][j] = exp2f(vv[b][j] - M); ts += vv[b][j]; }
        ts += __shfl_xor(ts, 16, 64);
        ts += __shfl_xor(ts, 32, 64);
        S += ts;

        // ---- pack P: U[2b+p] = bf16pair(vv[b][2p], vv[b][2p+1]) via v_cvt_pk
        uint U0, U1, U2, U3, U4, U5, U6, U7;
        asm("v_cvt_pk_bf16_f32 %0, %1, %2" : "=v"(U0) : "v"(vv[0][0]), "v"(vv[0][1]));
        asm("v_cvt_pk_bf16_f32 %0, %1, %2" : "=v"(U1) : "v"(vv[0][2]), "v"(vv[0][3]));
        asm("v_cvt_pk_bf16_f32 %0, %1, %2" : "=v"(U2) : "v"(vv[1][0]), "v"(vv[1][1]));
        asm("v_cvt_pk_bf16_f32 %0, %1, %2" : "=v"(U3) : "v"(vv[1][2]), "v"(vv[1][3]));
        asm("v_cvt_pk_bf16_f32 %0, %1, %2" : "=v"(U4) : "v"(vv[2][0]), "v"(vv[2][1]));
        asm("v_cvt_pk_bf16_f32 %0, %1, %2" : "=v"(U5) : "v"(vv[2][2]), "v"(vv[2][3]));
        asm("v_cvt_pk_bf16_f32 %0, %1, %2" : "=v"(U6) : "v"(vv[3][0]), "v"(vv[3][1]));
        asm("v_cvt_pk_bf16_f32 %0, %1, %2" : "=v"(U7) : "v"(vv[3][2]), "v"(vv[3][3]));

        // ---- in-register P exchange: pa0 = P[lq][keys lg*8..+7], pa1 = keys 32+lg*8..+7
        uint ra, rb;
        ra = (uint)__shfl((int)U0, sl0); rb = (uint)__shfl((int)U2, sl0);
        uint p00 = hi ? rb : ra;
        ra = (uint)__shfl((int)U1, sl0); rb = (uint)__shfl((int)U3, sl0);
        uint p01 = hi ? rb : ra;
        ra = (uint)__shfl((int)U0, sl1); rb = (uint)__shfl((int)U2, sl1);
        uint p02 = hi ? rb : ra;
        ra = (uint)__shfl((int)U1, sl1); rb = (uint)__shfl((int)U3, sl1);
        uint p03 = hi ? rb : ra;
        ra = (uint)__shfl((int)U4, sl0); rb = (uint)__shfl((int)U6, sl0);
        uint p10 = hi ? rb : ra;
        ra = (uint)__shfl((int)U5, sl0); rb = (uint)__shfl((int)U7, sl0);
        uint p11 = hi ? rb : ra;
        ra = (uint)__shfl((int)U4, sl1); rb = (uint)__shfl((int)U6, sl1);
        uint p12 = hi ? rb : ra;
        ra = (uint)__shfl((int)U5, sl1); rb = (uint)__shfl((int)U7, sl1);
        uint p13 = hi ? rb : ra;
        uint4 pu0 = {p00, p01, p02, p03};
        uint4 pu1 = {p10, p11, p12, p13};
        bf16x8 pa0 = __builtin_bit_cast(bf16x8, pu0);
        bf16x8 pa1 = __builtin_bit_cast(bf16x8, pu1);

        // ---- PV: A = P (in-register), B = V^T (in-register)
        {
            __builtin_amdgcn_s_setprio(1);
#pragma unroll
            for (int db = 0; db < 4; ++db) {
                o[db] = __builtin_amdgcn_mfma_f32_16x16x32_bf16(pa0, vf0[db], o[db], 0, 0, 0);
                o[db] = __builtin_amdgcn_mfma_f32_16x16x32_bf16(pa1, vf1[db], o[db], 0, 0, 0);
            }
            __builtin_amdgcn_s_setprio(0);
        }
        // prefetch next V tile into registers (hidden under next tile's QK^T+softmax)
        if (tt + 1 < tend) loadV(tt + 1);
    }

    // ---- write partials: o[db][j] is row n0+w*16+lg*4+j, dim db*16+lq
#pragma unroll
    for (int db = 0; db < 4; ++db)
#pragma unroll
        for (int j = 0; j < 4; ++j) {
            int r = n0 + w * 16 + lg * 4 + j;
            opart[((size_t)ks * NN + r) * HH + head * HD + db * 16 + lq] = o[db][j];
        }
    if (l < 16) {
        int r = n0 + w * 16 + l;
        Mp[((size_t)ks * NHH + head) * NN + r] = M;
        Sp[((size_t)ks * NHH + head) * NN + r] = S;
    }
}

// combine 3 partials -> bf16 attention output (log2-space M)
__global__ __launch_bounds__(256) void attn_combine(const float* __restrict__ opart,
                                                    const float* __restrict__ Mp,
                                                    const float* __restrict__ Sp,
                                                    ushort* __restrict__ aob) {
    int i = blockIdx.x * 256 + threadIdx.x;
    int row = i >> 9, col = i & 511;
    int head = col >> 6;
    float m0 = Mp[(size_t)head * NN + row];
    float m1 = Mp[((size_t)NHH + head) * NN + row];
    float m2 = Mp[((size_t)2 * NHH + head) * NN + row];
    float s0 = Sp[(size_t)head * NN + row];
    float s1 = Sp[((size_t)NHH + head) * NN + row];
    float s2 = Sp[((size_t)2 * NHH + head) * NN + row];
    float m = fmaxf(m0, fmaxf(m1, m2));
    float w0 = exp2f(m0 - m), w1 = exp2f(m1 - m), w2 = exp2f(m2 - m);
    float num = opart[(size_t)row * HH + col] * w0
              + opart[((size_t)NN + row) * HH + col] * w1
              + opart[((size_t)2 * NN + row) * HH + col] * w2;
    float den = s0 * w0 + s1 * w1 + s2 * w2;
    aob[i] = f2bf(num / den);
}

// ---------------- LayerNorm(out = LN(a + b) * g + be); optional bf16 copy
template<int BF16OUT>
__global__ __launch_bounds__(256) void ln_kernel(const float* __restrict__ a,
                                                 const float* __restrict__ b,
                                                 const float* __restrict__ g,
                                                 const float* __restrict__ be,
                                                 float* __restrict__ out,
                                                 ushort* __restrict__ outb) {
    int row = blockIdx.x * 4 + (threadIdx.x >> 6);
    int lane = threadIdx.x & 63;
    const float* pa = a + (size_t)row * HH;
    const float* pb = b + (size_t)row * HH;
    float x[8];
    float s = 0.f;
#pragma unroll
    for (int i = 0; i < 8; ++i) { x[i] = pa[lane + i * 64] + pb[lane + i * 64]; s += x[i]; }
#pragma unroll
    for (int off = 32; off > 0; off >>= 1) s += __shfl_xor(s, off, 64);
    float mean = s * (1.f / 512.f);
    float vs = 0.f;
#pragma unroll
    for (int i = 0; i < 8; ++i) { float d = x[i] - mean; vs += d * d; }
#pragma unroll
    for (int off = 32; off > 0; off >>= 1) vs += __shfl_xor(vs, off, 64);
    float rs = rsqrtf(vs * (1.f / 512.f) + 1e-5f);
    float* po = out + (size_t)row * HH;
    ushort* pob = outb + (size_t)row * HH;
#pragma unroll
    for (int i = 0; i < 8; ++i) {
        float v = (x[i] - mean) * rs * g[lane + i * 64] + be[lane + i * 64];
        po[lane + i * 64] = v;
        if (BF16OUT) pob[lane + i * 64] = f2bf(v);
    }
}

extern "C" void kernel_launch(void* const* d_in, const int* in_sizes, int n_in,
                              void* d_out, int out_size, void* d_ws, size_t ws_size,
                              hipStream_t stream) {
    const float* x   = (const float*)d_in[0];
    const int*  eidx = (const int*)d_in[1];
    const float* ea  = (const float*)d_in[2];
    const float* Wn = (const float*)d_in[3];  const float* bn = (const float*)d_in[4];
    const float* We = (const float*)d_in[5];  const float* be = (const float*)d_in[6];
    const float* Wq = (const float*)d_in[7];  const float* bq = (const float*)d_in[8];
    const float* Wk = (const float*)d_in[9];  const float* bk = (const float*)d_in[10];
    const float* Wv = (const float*)d_in[11]; const float* bv = (const float*)d_in[12];
    const float* Wo = (const float*)d_in[13]; const float* bo = (const float*)d_in[14];
    const float* W1 = (const float*)d_in[15]; const float* b1 = (const float*)d_in[16];
    const float* W2 = (const float*)d_in[17]; const float* b2 = (const float*)d_in[18];
    const float* g1 = (const float*)d_in[19]; const float* be1 = (const float*)d_in[20];
    const float* g2 = (const float*)d_in[21]; const float* be2 = (const float*)d_in[22];
    float* out = (float*)d_out;

    // workspace carve (bytes, 256-aligned)
    char* base = (char*)d_ws;
    size_t off = 0;
    auto carve = [&](size_t bytes) { void* p = base + off; off = (off + bytes + 255) & ~(size_t)255; return p; };
    float*  h    = (float*)carve((size_t)NN * HH * 4);
    ushort* hb   = (ushort*)carve((size_t)NN * HH * 2);
    // [po, ff1b, qb, kbf] contiguous 16 MB -> aliased as lastE during setup;
    // [po, ff1b] = 12 MB -> aliased as opart (3 x 4 MB) during attention
    float*  po   = (float*)carve((size_t)NN * HH * 4);
    ushort* ff1b = (ushort*)carve((size_t)NN * 4 * HH * 2);
    ushort* qb   = (ushort*)carve((size_t)NN * HH * 2);
    ushort* kbf  = (ushort*)carve((size_t)NN * HH * 2);
    ushort* vtb  = (ushort*)carve((size_t)NN * HH * 2);
    ushort* aob  = (ushort*)carve((size_t)NN * HH * 2);
    ushort* xb   = (ushort*)carve((size_t)NN * NF_ * 2);
    ushort* WnT  = (ushort*)carve((size_t)HH * NF_ * 2);
    ushort* WqkvT= (ushort*)carve((size_t)3 * HH * HH * 2);
    ushort* WoT  = (ushort*)carve((size_t)HH * HH * 2);
    ushort* W1T  = (ushort*)carve((size_t)4 * HH * HH * 2);
    ushort* W2T  = (ushort*)carve((size_t)4 * HH * HH * 2);
    float*  bqkv = (float*)carve((size_t)3 * HH * 4);
    float*  eb   = (float*)carve((size_t)EE * NHH * 4);
    float*  csr_b= (float*)carve((size_t)EE * NHH * 4);
    float*  Mp   = (float*)carve((size_t)KSPLIT * NHH * NN * 4);
    float*  Sp   = (float*)carve((size_t)KSPLIT * NHH * NN * 4);
    int* cnt     = (int*)carve((size_t)NN * 4);
    int* rowptr  = (int*)carve((size_t)(NN + 1) * 4);
    int* csr_dst = (int*)carve((size_t)EE * 4);
    int* cnt2    = (int*)carve((size_t)NN * NTILE_TOT * 4);
    int* rtptr   = (int*)carve((size_t)(NN * NTILE_TOT + 1) * 4);
    int* rtoff   = (int*)carve((size_t)NN * NTILE_TOT * 4);
    int* lastE = (int*)po;            // setup alias (po+ff1b+qb+kbf = 16 MB)
    float* opart = (float*)po;        // attention partials alias po+ff1b (12 MB)

    // ---- setup
    hipMemsetAsync(lastE, 0xFF, (size_t)NN * NN * 4, stream);
    hipMemsetAsync(cnt, 0, (size_t)NN * 4, stream);
    hipMemsetAsync(cnt2, 0, (size_t)NN * NTILE_TOT * 4, stream);

    xcvt<<<(NN * NF_ + 255) / 256, 256, 0, stream>>>(x, xb, NN * NF_);
    wtrans<<<dim3(HH / 32, NF_ / 32), 256, 0, stream>>>(Wn, WnT, NF_, HH, 0);
    wtrans<<<dim3(HH / 32, HH / 32), 256, 0, stream>>>(Wq, WqkvT, HH, HH, 0);
    wtrans<<<dim3(HH / 32, HH / 32), 256, 0, stream>>>(Wk, WqkvT, HH, HH, 512);
    wtrans<<<dim3(HH / 32, HH / 32), 256, 0, stream>>>(Wv, WqkvT, HH, HH, 1024);
    wtrans<<<dim3(HH / 32, HH / 32), 256, 0, stream>>>(Wo, WoT, HH, HH, 0);
    wtrans<<<dim3(4 * HH / 32, HH / 32), 256, 0, stream>>>(W1, W1T, HH, 4 * HH, 0);
    wtrans<<<dim3(HH / 32, 4 * HH / 32), 256, 0, stream>>>(W2, W2T, 4 * HH, HH, 0);
    bconcat<<<6, 256, 0, stream>>>(bq, bk, bv, bqkv);

    ebias_kernel<<<EE / 256, 256, 0, stream>>>(ea, We, be, eb);
    amax_kernel<<<EE / 256, 256, 0, stream>>>(eidx, lastE);
    count_kernel<<<EE / 256, 256, 0, stream>>>(eidx, lastE, cnt);
    scan2048<<<1, 256, 0, stream>>>(cnt, rowptr);
    rt_count<<<EE / 256, 256, 0, stream>>>(eidx, lastE, cnt2);
    rt_scan<<<NN / 256, 256, 0, stream>>>(rowptr, cnt2, rtptr, rtoff);
    rt_fill<<<EE / 256, 256, 0, stream>>>(eidx, lastE, eb, rtoff, csr_dst, csr_b);

    // h = x @ Wn + bn  (f32 + bf16)
    gemm_mfma<64, 64, 1, 0><<<dim3(HH / 64, NN / 64), 256, 0, stream>>>(
        xb, WnT, bn, h, hb, nullptr, nullptr, nullptr, NN, HH, NF_);

    // ---- transformer layers (attention bias-path A/B continues: even=LDS, odd=register)
    for (int d = 0; d < DEPTH; ++d) {
        gemm_mfma<64, 64, 3, 0><<<dim3(3 * HH / 64, NN / 64), 256, 0, stream>>>(
            hb, WqkvT, bqkv, nullptr, nullptr, qb, kbf, vtb, NN, 3 * HH, HH);
        if (d & 1)
            attn_mfma<0><<<dim3(32 * NHH * KSPLIT), 256, 0, stream>>>(
                qb, kbf, vtb, rtptr, csr_dst, csr_b, opart, Mp, Sp);
        else
            attn_mfma<1><<<dim3(32 * NHH * KSPLIT), 256, 0, stream>>>(
                qb, kbf, vtb, rtptr, csr_dst, csr_b, opart, Mp, Sp);
        attn_combine<<<NN * HH / 256, 256, 0, stream>>>(opart, Mp, Sp, aob);
        gemm_mfma<32, 64, 0, 0><<<dim3(HH / 64, NN / 32), 256, 0, stream>>>(
            aob, WoT, bo, po, nullptr, nullptr, nullptr, nullptr, NN, HH, HH);
        ln_kernel<1><<<NN / 4, 256, 0, stream>>>(h, po, g1, be1, h, hb);
        gemm_mfma<64, 64, 2, 1><<<dim3(4 * HH / 64, NN / 64), 256, 0, stream>>>(
            hb, W1T, b1, nullptr, ff1b, nullptr, nullptr, nullptr, NN, 4 * HH, HH);
        gemm_mfma<32, 64, 0, 0><<<dim3(HH / 64, NN / 32), 256, 0, stream>>>(
            ff1b, W2T, b2, po, nullptr, nullptr, nullptr, nullptr, NN, HH, 4 * HH);
        float* dst = (d == DEPTH - 1) ? out : h;
        ln_kernel<1><<<NN / 4, 256, 0, stream>>>(h, po, g2, be2, dst, hb);
    }
    (void)in_sizes; (void)n_in; (void)out_size; (void)ws_size;
}

// Round 12
// 574.834 us; speedup vs baseline: 1.2975x; 1.2975x over previous
//
#include <hip/hip_runtime.h>
#include <hip/hip_bf16.h>

// Problem constants (fixed shapes)
#define NN 2048      // nodes
#define EE 65536     // edges
#define NF_ 128
#define HH 512
#define NHH 8
#define HD 64
#define DEPTH 5
#define KSPLIT 3
#define NTILE_TOT (NN / 64)      // 32
#define LOG2E 1.4426950408889634f
#define QSCALE 0.18033688011112042f   // 0.125 * log2e, folded into Q at projection

typedef __attribute__((ext_vector_type(8))) short bf16x8;
typedef __attribute__((ext_vector_type(4))) float f32x4;

__device__ __forceinline__ ushort f2bf(float x) {
    uint u = __builtin_bit_cast(uint, x);
    u += 0x7fffu + ((u >> 16) & 1u);
    return (ushort)(u >> 16);
}

#define GLD16(gp, lp)                                                          \
    __builtin_amdgcn_global_load_lds(                                          \
        (const __attribute__((address_space(1))) unsigned int*)(gp),           \
        (__attribute__((address_space(3))) unsigned int*)(lp), 16, 0, 0)

// ---------------- bf16 MFMA GEMM: C = A[M,K] @ Bt[N,K]^T + bias
// OUT: 0 = f32 C; 1 = f32 C + bf16 Cb; 2 = bf16 Cb; 3 = qkv scatter (Q pre-scaled by QSCALE)
template<int BM, int BN, int OUT, int RELU>
__global__ __launch_bounds__(256) void gemm_mfma(const ushort* __restrict__ A,
                                                 const ushort* __restrict__ Bt,
                                                 const float* __restrict__ bias,
                                                 float* __restrict__ C,
                                                 ushort* __restrict__ Cb,
                                                 ushort* __restrict__ qb,
                                                 ushort* __restrict__ kb,
                                                 ushort* __restrict__ vtb,
                                                 int M, int N, int K) {
    constexpr int WM = BM / 2, WN = BN / 2;
    constexpr int MR = BM / 32, NR = BN / 32;
    __shared__ __align__(16) ushort As[2][BM * 64];
    __shared__ __align__(16) ushort Bs[2][BN * 64];
    const int t = threadIdx.x;
    const int w = t >> 6, l = t & 63;
    const int wr = w >> 1, wc = w & 1;
    const int m0 = blockIdx.y * BM, n0 = blockIdx.x * BN;

    f32x4 acc[MR][NR];
#pragma unroll
    for (int m = 0; m < MR; ++m)
#pragma unroll
        for (int n = 0; n < NR; ++n) acc[m][n] = (f32x4){0.f, 0.f, 0.f, 0.f};

    const int srow = t >> 3, sch = t & 7;
    auto stage = [&](int buf, int kt) {
#pragma unroll
        for (int r = 0; r < MR; ++r) {
            int rr = r * 32 + srow;
            int c = sch ^ (rr & 7);                   // inverse swizzle on SOURCE
            GLD16(A + (size_t)(m0 + rr) * K + kt * 64 + c * 8,
                  &As[buf][rr * 64 + sch * 8]);       // linear LDS dest
        }
#pragma unroll
        for (int r = 0; r < NR; ++r) {
            int rr = r * 32 + srow;
            int c = sch ^ (rr & 7);
            GLD16(Bt + (size_t)(n0 + rr) * K + kt * 64 + c * 8,
                  &Bs[buf][rr * 64 + sch * 8]);
        }
    };

    stage(0, 0);
    const int NT = K / 64;
    for (int kt = 0; kt < NT; ++kt) {
        __syncthreads();
        if (kt + 1 < NT) stage((kt + 1) & 1, kt + 1);
        const int buf = kt & 1;
#pragma unroll
        for (int kk = 0; kk < 2; ++kk) {
            bf16x8 af[MR], bfr[NR];
#pragma unroll
            for (int m = 0; m < MR; ++m) {
                int R = wr * WM + m * 16 + (l & 15);
                int c = kk * 4 + (l >> 4);
                af[m] = *(const bf16x8*)&As[buf][R * 64 + (c ^ (R & 7)) * 8];  // swizzled read
            }
#pragma unroll
            for (int n = 0; n < NR; ++n) {
                int R = wc * WN + n * 16 + (l & 15);
                int c = kk * 4 + (l >> 4);
                bfr[n] = *(const bf16x8*)&Bs[buf][R * 64 + (c ^ (R & 7)) * 8];
            }
#pragma unroll
            for (int m = 0; m < MR; ++m)
#pragma unroll
                for (int n = 0; n < NR; ++n)
                    acc[m][n] = __builtin_amdgcn_mfma_f32_16x16x32_bf16(af[m], bfr[n], acc[m][n], 0, 0, 0);
        }
    }

    // epilogue: C/D layout col=l&15, row=(l>>4)*4+j
#pragma unroll
    for (int m = 0; m < MR; ++m) {
        int row = m0 + wr * WM + m * 16 + (l >> 4) * 4;
#pragma unroll
        for (int n = 0; n < NR; ++n) {
            int col = n0 + wc * WN + n * 16 + (l & 15);
            float bv = bias[col];
            float v4[4];
#pragma unroll
            for (int j = 0; j < 4; ++j) {
                float vv = acc[m][n][j] + bv;
                if (RELU) vv = fmaxf(vv, 0.f);
                v4[j] = vv;
            }
            if (OUT == 0) {
#pragma unroll
                for (int j = 0; j < 4; ++j) C[(size_t)(row + j) * N + col] = v4[j];
            } else if (OUT == 1) {
#pragma unroll
                for (int j = 0; j < 4; ++j) {
                    C[(size_t)(row + j) * N + col] = v4[j];
                    Cb[(size_t)(row + j) * N + col] = f2bf(v4[j]);
                }
            } else if (OUT == 2) {
#pragma unroll
                for (int j = 0; j < 4; ++j) Cb[(size_t)(row + j) * N + col] = f2bf(v4[j]);
            } else {
                int type = col >> 9, head = (col >> 6) & 7, dd = col & 63;
                if (type == 2) {
                    // packed transposed V store: 4 consecutive rows -> one 8B store
                    uint2 pk2;
                    pk2.x = (uint)f2bf(v4[0]) | ((uint)f2bf(v4[1]) << 16);
                    pk2.y = (uint)f2bf(v4[2]) | ((uint)f2bf(v4[3]) << 16);
                    *(uint2*)&vtb[((size_t)head * 64 + dd) * NN + row] = pk2;
                } else if (type == 0) {
#pragma unroll
                    for (int j = 0; j < 4; ++j)
                        qb[((size_t)head * NN + row + j) * 64 + dd] = f2bf(v4[j] * QSCALE);
                } else {
#pragma unroll
                    for (int j = 0; j < 4; ++j)
                        kb[((size_t)head * NN + row + j) * 64 + dd] = f2bf(v4[j]);
                }
            }
        }
    }
}

// ---------------- setup converts
__global__ __launch_bounds__(256) void xcvt(const float* __restrict__ x, ushort* __restrict__ xb, int n) {
    int i = blockIdx.x * 256 + threadIdx.x;
    if (i < n) xb[i] = f2bf(x[i]);
}

__global__ __launch_bounds__(256) void wtrans(const float* __restrict__ W, ushort* __restrict__ WT,
                                              int K, int N, int rowoff) {
    __shared__ float tile[32][33];
    int n0 = blockIdx.x * 32, k0 = blockIdx.y * 32;
    int tc = threadIdx.x & 31, tr = threadIdx.x >> 5;
#pragma unroll
    for (int i = 0; i < 32; i += 8) tile[tr + i][tc] = W[(size_t)(k0 + tr + i) * N + n0 + tc];
    __syncthreads();
#pragma unroll
    for (int i = 0; i < 32; i += 8)
        WT[(size_t)(rowoff + n0 + tr + i) * K + k0 + tc] = f2bf(tile[tc][tr + i]);
}

__global__ __launch_bounds__(256) void bconcat(const float* __restrict__ a, const float* __restrict__ b,
                                               const float* __restrict__ c, float* __restrict__ o) {
    int i = blockIdx.x * 256 + threadIdx.x;
    if (i < 1536) o[i] = i < 512 ? a[i] : (i < 1024 ? b[i - 512] : c[i - 1024]);
}

// ---------------- e_bias = edge_attr @ We + be
__global__ __launch_bounds__(256) void ebias_kernel(const float* __restrict__ ea,
                                                    const float* __restrict__ We,
                                                    const float* __restrict__ be,
                                                    float* __restrict__ eb) {
    int e = blockIdx.x * 256 + threadIdx.x;
    float a[16];
#pragma unroll
    for (int i = 0; i < 16; ++i) a[i] = ea[(size_t)e * 16 + i];
#pragma unroll
    for (int j = 0; j < 8; ++j) {
        float s = be[j];
#pragma unroll
        for (int i = 0; i < 16; ++i) s += a[i] * We[i * 8 + j];
        eb[(size_t)e * 8 + j] = s;
    }
}

// ---------------- dedupe: last edge index wins per (src,dst)
__global__ __launch_bounds__(256) void amax_kernel(const int* __restrict__ eidx, int* __restrict__ lastE) {
    int e = blockIdx.x * 256 + threadIdx.x;
    int s = eidx[e], d = eidx[EE + e];
    atomicMax(&lastE[s * NN + d], e);
}

__global__ __launch_bounds__(256) void count_kernel(const int* __restrict__ eidx,
                                                    const int* __restrict__ lastE,
                                                    int* __restrict__ cnt) {
    int e = blockIdx.x * 256 + threadIdx.x;
    int s = eidx[e], d = eidx[EE + e];
    if (lastE[s * NN + d] == e) atomicAdd(&cnt[s], 1);
}

__global__ __launch_bounds__(256) void scan2048(const int* __restrict__ cnt,
                                                int* __restrict__ rowptr) {
    __shared__ int sums[256];
    int t = threadIdx.x;
    int loc[8];
    int s = 0;
#pragma unroll
    for (int i = 0; i < 8; ++i) { loc[i] = s; s += cnt[t * 8 + i]; }
    sums[t] = s;
    __syncthreads();
    for (int off = 1; off < 256; off <<= 1) {
        int v = (t >= off) ? sums[t - off] : 0;
        __syncthreads();
        sums[t] += v;
        __syncthreads();
    }
    int base = (t == 0) ? 0 : sums[t - 1];
#pragma unroll
    for (int i = 0; i < 8; ++i) rowptr[t * 8 + i] = base + loc[i];
    if (t == 255) rowptr[NN] = sums[255];
}

// ---------------- (row, key-tile) bucketing of bias entries (layer-invariant)
__global__ __launch_bounds__(256) void rt_count(const int* __restrict__ eidx,
                                                const int* __restrict__ lastE,
                                                int* __restrict__ cnt2) {
    int e = blockIdx.x * 256 + threadIdx.x;
    int s = eidx[e], d = eidx[EE + e];
    if (lastE[s * NN + d] == e) atomicAdd(&cnt2[s * NTILE_TOT + (d >> 6)], 1);
}

__global__ __launch_bounds__(256) void rt_scan(const int* __restrict__ rowptr,
                                               const int* __restrict__ cnt2,
                                               int* __restrict__ rtptr,
                                               int* __restrict__ rtoff) {
    int row = blockIdx.x * 256 + threadIdx.x;
    if (row >= NN) return;
    int base = rowptr[row];
#pragma unroll
    for (int t = 0; t < NTILE_TOT; ++t) {
        rtptr[row * NTILE_TOT + t] = base;
        rtoff[row * NTILE_TOT + t] = base;
        base += cnt2[row * NTILE_TOT + t];
    }
    if (row == NN - 1) rtptr[NN * NTILE_TOT] = base;
}

// fill buckets: dst stored relative to tile (0..63); bias pre-scaled by log2e
__global__ __launch_bounds__(256) void rt_fill(const int* __restrict__ eidx,
                                               const int* __restrict__ lastE,
                                               const float* __restrict__ eb,
                                               int* __restrict__ rtoff,
                                               int* __restrict__ csr_dst,
                                               float* __restrict__ csr_b) {
    int e = blockIdx.x * 256 + threadIdx.x;
    int s = eidx[e], d = eidx[EE + e];
    if (lastE[s * NN + d] == e) {
        int pos = atomicAdd(&rtoff[s * NTILE_TOT + (d >> 6)], 1);
        csr_dst[pos] = d & 63;
#pragma unroll
        for (int j = 0; j < 8; ++j) csr_b[(size_t)pos * 8 + j] = eb[(size_t)e * 8 + j] * LOG2E;
    }
}

// ---------------- split-K flash attention (round-10 structure, BIASLDS=1 fixed)
// grid 768 = qblk(32) x head(8) x ks(3), XCD-chunk swizzled. 1 barrier/tile.
__global__ __launch_bounds__(256) void attn_mfma(const ushort* __restrict__ qb,
                                                 const ushort* __restrict__ kb,
                                                 const ushort* __restrict__ vtb,
                                                 const int* __restrict__ rtptr,
                                                 const int* __restrict__ csr_dst,
                                                 const float* __restrict__ csr_b,
                                                 float* __restrict__ opart,
                                                 float* __restrict__ Mp,
                                                 float* __restrict__ Sp) {
    const int id = blockIdx.x;
    const int f = (id & 7) * 96 + (id >> 3);    // 768 blocks, 96/XCD
    const int n0 = (f & 31) * 64;
    const int head = (f >> 5) & 7;
    const int ks = f >> 8;                       // 0..2
    const int tstart = (ks * 32) / 3, tend = ((ks + 1) * 32) / 3;   // 10/11/11 tiles
    const int t = threadIdx.x;
    const int w = t >> 6, l = t & 63;
    const int lq = l & 15, lg = l >> 4;

    __shared__ __align__(16) ushort Ks2[2][64 * 64];   // K dbuf, swizzled
    __shared__ __align__(16) ushort Vs2[2][64 * 64];   // V dbuf, swizzled
    __shared__ __align__(16) ushort Bb[4][16 * 72];    // per-wave bias mini-tile (bf16)
    __shared__ int Rt[64][12];                         // bucket bounds per block row

    // persistent Q fragments (pre-scaled by QSCALE): rows n0 + w*16 + lq
    bf16x8 qf0, qf1;
    {
        int r = n0 + w * 16 + lq;
        const ushort* qp = qb + ((size_t)head * NN + r) * HD + lg * 8;
        qf0 = *(const bf16x8*)qp;
        qf1 = *(const bf16x8*)(qp + 32);
    }
    const int ntile = tend - tstart;
    for (int i = t; i < 64 * 12; i += 256) {
        int r = i / 12, c = i % 12;
        if (c <= ntile) Rt[r][c] = rtptr[(n0 + r) * NTILE_TOT + tstart + c];
    }
    float M = -1e30f, S = 0.f;
    f32x4 o[4];
#pragma unroll
    for (int db = 0; db < 4; ++db) o[db] = (f32x4){0.f, 0.f, 0.f, 0.f};

    auto stageK = [&](int buf, int tile) {
        int m0k = tile * 64;
#pragma unroll
        for (int s = 0; s < 2; ++s) {
            int slot = t + s * 256;
            int rr = slot >> 3, blk = slot & 7, sb = blk ^ (rr & 7);
            GLD16(kb + ((size_t)head * NN + m0k + rr) * 64 + sb * 8,
                  &Ks2[buf][rr * 64 + blk * 8]);
        }
    };
    auto stageV = [&](int buf, int tile) {
        int m0k = tile * 64;
#pragma unroll
        for (int s = 0; s < 2; ++s) {
            int slot = t + s * 256;
            int rr = slot >> 3, blk = slot & 7, sb = blk ^ (rr & 7);
            GLD16(vtb + ((size_t)head * 64 + rr) * NN + m0k + sb * 8,
                  &Vs2[buf][rr * 64 + blk * 8]);
        }
    };

    stageK(0, tstart);
    stageV(0, tstart);
    __syncthreads();   // tile 0 landed, Rt visible

    // P lane-exchange constants (dest lane lg pulls from src lane ((2lg+c)&3)*16+lq)
    const int sl0 = (((lg << 1) + 0) & 3) * 16 + lq;
    const int sl1 = (((lg << 1) + 1) & 3) * 16 + lq;
    const int hi = lg & 2;

    for (int tt = tstart; tt < tend; ++tt) {
        const int tl = tt - tstart;
        const int cb = tl & 1;
        if (tt + 1 < tend) { stageK(cb ^ 1, tt + 1); stageV(cb ^ 1, tt + 1); }

        const int rq = w * 16 + lq;
        const int p0 = Rt[rq][tl], p1 = Rt[rq][tl + 1];

        // zero this wave's bias mini-tile (wave-coherent, no barrier needed)
        for (int i = l; i < 144; i += 64)
            *(uint4*)&Bb[w][i * 8] = (uint4){0, 0, 0, 0};
        // scatter bucket entries (lg==0 lanes only; ~1 entry/row avg)
        if (lg == 0) {
            for (int e = p0; e < p1; ++e)
                Bb[w][lq * 72 + csr_dst[e]] = f2bf(csr_b[(size_t)e * 8 + head]);
        }

        // ---- QK^T (swapped): vv[b][j] = score[q=lq][key = b*16 + lg*4 + j]
        f32x4 vv[4];
        {
            const ushort* Kb_ = &Ks2[cb][0];
            __builtin_amdgcn_s_setprio(1);
#pragma unroll
            for (int b = 0; b < 4; ++b) {
                int key = b * 16 + lq;
                bf16x8 k0 = *(const bf16x8*)&Kb_[key * 64 + ((lg ^ (key & 7)) * 8)];
                bf16x8 k1 = *(const bf16x8*)&Kb_[key * 64 + (((lg + 4) ^ (key & 7)) * 8)];
                f32x4 s_ = {0.f, 0.f, 0.f, 0.f};
                s_ = __builtin_amdgcn_mfma_f32_16x16x32_bf16(k0, qf0, s_, 0, 0, 0);
                s_ = __builtin_amdgcn_mfma_f32_16x16x32_bf16(k1, qf1, s_, 0, 0, 0);
                vv[b] = s_;
            }
            __builtin_amdgcn_s_setprio(0);
        }

        // ---- bias merge from mini-tile
#pragma unroll
        for (int b = 0; b < 4; ++b) {
            uint2 bb = *(const uint2*)&Bb[w][lq * 72 + b * 16 + lg * 4];
            vv[b][0] += __builtin_bit_cast(float, bb.x << 16);
            vv[b][1] += __builtin_bit_cast(float, bb.x & 0xffff0000u);
            vv[b][2] += __builtin_bit_cast(float, bb.y << 16);
            vv[b][3] += __builtin_bit_cast(float, bb.y & 0xffff0000u);
        }

        // ---- wave-local online softmax (log2 space), exact defer-rescale
        float mx = vv[0][0];
#pragma unroll
        for (int b = 0; b < 4; ++b)
#pragma unroll
            for (int j = 0; j < 4; ++j) mx = fmaxf(mx, vv[b][j]);
        mx = fmaxf(mx, __shfl_xor(mx, 16, 64));
        mx = fmaxf(mx, __shfl_xor(mx, 32, 64));
        if (!__all(mx <= M)) {
            float Mn = fmaxf(M, mx);
            float fr = exp2f(M - Mn);
            M = Mn;
            S *= fr;
#pragma unroll
            for (int j = 0; j < 4; ++j) {
                float Fj = __shfl(fr, lg * 4 + j, 64);
                o[0][j] *= Fj; o[1][j] *= Fj; o[2][j] *= Fj; o[3][j] *= Fj;
            }
        }
        float ts = 0.f;
#pragma unroll
        for (int b = 0; b < 4; ++b)
#pragma unroll
            for (int j = 0; j < 4; ++j) { vv[b][j] = exp2f(vv[b][j] - M); ts += vv[b][j]; }
        ts += __shfl_xor(ts, 16, 64);
        ts += __shfl_xor(ts, 32, 64);
        S += ts;

        // ---- pack P: U[2b+p] = bf16pair(vv[b][2p], vv[b][2p+1]) via v_cvt_pk
        uint U0, U1, U2, U3, U4, U5, U6, U7;
        asm("v_cvt_pk_bf16_f32 %0, %1, %2" : "=v"(U0) : "v"(vv[0][0]), "v"(vv[0][1]));
        asm("v_cvt_pk_bf16_f32 %0, %1, %2" : "=v"(U1) : "v"(vv[0][2]), "v"(vv[0][3]));
        asm("v_cvt_pk_bf16_f32 %0, %1, %2" : "=v"(U2) : "v"(vv[1][0]), "v"(vv[1][1]));
        asm("v_cvt_pk_bf16_f32 %0, %1, %2" : "=v"(U3) : "v"(vv[1][2]), "v"(vv[1][3]));
        asm("v_cvt_pk_bf16_f32 %0, %1, %2" : "=v"(U4) : "v"(vv[2][0]), "v"(vv[2][1]));
        asm("v_cvt_pk_bf16_f32 %0, %1, %2" : "=v"(U5) : "v"(vv[2][2]), "v"(vv[2][3]));
        asm("v_cvt_pk_bf16_f32 %0, %1, %2" : "=v"(U6) : "v"(vv[3][0]), "v"(vv[3][1]));
        asm("v_cvt_pk_bf16_f32 %0, %1, %2" : "=v"(U7) : "v"(vv[3][2]), "v"(vv[3][3]));

        // ---- in-register P exchange: pa0 = P[lq][keys lg*8..+7], pa1 = keys 32+lg*8..+7
        uint ra, rb;
        ra = (uint)__shfl((int)U0, sl0); rb = (uint)__shfl((int)U2, sl0);
        uint p00 = hi ? rb : ra;
        ra = (uint)__shfl((int)U1, sl0); rb = (uint)__shfl((int)U3, sl0);
        uint p01 = hi ? rb : ra;
        ra = (uint)__shfl((int)U0, sl1); rb = (uint)__shfl((int)U2, sl1);
        uint p02 = hi ? rb : ra;
        ra = (uint)__shfl((int)U1, sl1); rb = (uint)__shfl((int)U3, sl1);
        uint p03 = hi ? rb : ra;
        ra = (uint)__shfl((int)U4, sl0); rb = (uint)__shfl((int)U6, sl0);
        uint p10 = hi ? rb : ra;
        ra = (uint)__shfl((int)U5, sl0); rb = (uint)__shfl((int)U7, sl0);
        uint p11 = hi ? rb : ra;
        ra = (uint)__shfl((int)U4, sl1); rb = (uint)__shfl((int)U6, sl1);
        uint p12 = hi ? rb : ra;
        ra = (uint)__shfl((int)U5, sl1); rb = (uint)__shfl((int)U7, sl1);
        uint p13 = hi ? rb : ra;
        uint4 pu0 = {p00, p01, p02, p03};
        uint4 pu1 = {p10, p11, p12, p13};
        bf16x8 pa0 = __builtin_bit_cast(bf16x8, pu0);
        bf16x8 pa1 = __builtin_bit_cast(bf16x8, pu1);

        // ---- PV: A = P (in-register), B = V^T from LDS
        {
            const ushort* Vb_ = &Vs2[cb][0];
            __builtin_amdgcn_s_setprio(1);
#pragma unroll
            for (int db = 0; db < 4; ++db) {
                int dim = db * 16 + lq;
                bf16x8 v0 = *(const bf16x8*)&Vb_[dim * 64 + ((lg ^ (dim & 7)) * 8)];
                bf16x8 v1 = *(const bf16x8*)&Vb_[dim * 64 + (((lg + 4) ^ (dim & 7)) * 8)];
                o[db] = __builtin_amdgcn_mfma_f32_16x16x32_bf16(pa0, v0, o[db], 0, 0, 0);
                o[db] = __builtin_amdgcn_mfma_f32_16x16x32_bf16(pa1, v1, o[db], 0, 0, 0);
            }
            __builtin_amdgcn_s_setprio(0);
        }
        __syncthreads();   // next-tile stage landed; buffers free for reuse
    }

    // ---- write partials: o[db][j] is row n0+w*16+lg*4+j, dim db*16+lq
#pragma unroll
    for (int db = 0; db < 4; ++db)
#pragma unroll
        for (int j = 0; j < 4; ++j) {
            int r = n0 + w * 16 + lg * 4 + j;
            opart[((size_t)ks * NN + r) * HH + head * HD + db * 16 + lq] = o[db][j];
        }
    if (l < 16) {
        int r = n0 + w * 16 + l;
        Mp[((size_t)ks * NHH + head) * NN + r] = M;
        Sp[((size_t)ks * NHH + head) * NN + r] = S;
    }
}

// combine 3 partials -> bf16 attention output (log2-space M)
__global__ __launch_bounds__(256) void attn_combine(const float* __restrict__ opart,
                                                    const float* __restrict__ Mp,
                                                    const float* __restrict__ Sp,
                                                    ushort* __restrict__ aob) {
    int i = blockIdx.x * 256 + threadIdx.x;
    int row = i >> 9, col = i & 511;
    int head = col >> 6;
    float m0 = Mp[(size_t)head * NN + row];
    float m1 = Mp[((size_t)NHH + head) * NN + row];
    float m2 = Mp[((size_t)2 * NHH + head) * NN + row];
    float s0 = Sp[(size_t)head * NN + row];
    float s1 = Sp[((size_t)NHH + head) * NN + row];
    float s2 = Sp[((size_t)2 * NHH + head) * NN + row];
    float m = fmaxf(m0, fmaxf(m1, m2));
    float w0 = exp2f(m0 - m), w1 = exp2f(m1 - m), w2 = exp2f(m2 - m);
    float num = opart[(size_t)row * HH + col] * w0
              + opart[((size_t)NN + row) * HH + col] * w1
              + opart[((size_t)2 * NN + row) * HH + col] * w2;
    float den = s0 * w0 + s1 * w1 + s2 * w2;
    aob[i] = f2bf(num / den);
}

// ---------------- LayerNorm(out = LN(a + b) * g + be); optional bf16 copy
template<int BF16OUT>
__global__ __launch_bounds__(256) void ln_kernel(const float* __restrict__ a,
                                                 const float* __restrict__ b,
                                                 const float* __restrict__ g,
                                                 const float* __restrict__ be,
                                                 float* __restrict__ out,
                                                 ushort* __restrict__ outb) {
    int row = blockIdx.x * 4 + (threadIdx.x >> 6);
    int lane = threadIdx.x & 63;
    const float* pa = a + (size_t)row * HH;
    const float* pb = b + (size_t)row * HH;
    float x[8];
    float s = 0.f;
#pragma unroll
    for (int i = 0; i < 8; ++i) { x[i] = pa[lane + i * 64] + pb[lane + i * 64]; s += x[i]; }
#pragma unroll
    for (int off = 32; off > 0; off >>= 1) s += __shfl_xor(s, off, 64);
    float mean = s * (1.f / 512.f);
    float vs = 0.f;
#pragma unroll
    for (int i = 0; i < 8; ++i) { float d = x[i] - mean; vs += d * d; }
#pragma unroll
    for (int off = 32; off > 0; off >>= 1) vs += __shfl_xor(vs, off, 64);
    float rs = rsqrtf(vs * (1.f / 512.f) + 1e-5f);
    float* po = out + (size_t)row * HH;
    ushort* pob = outb + (size_t)row * HH;
#pragma unroll
    for (int i = 0; i < 8; ++i) {
        float v = (x[i] - mean) * rs * g[lane + i * 64] + be[lane + i * 64];
        po[lane + i * 64] = v;
        if (BF16OUT) pob[lane + i * 64] = f2bf(v);
    }
}

extern "C" void kernel_launch(void* const* d_in, const int* in_sizes, int n_in,
                              void* d_out, int out_size, void* d_ws, size_t ws_size,
                              hipStream_t stream) {
    const float* x   = (const float*)d_in[0];
    const int*  eidx = (const int*)d_in[1];
    const float* ea  = (const float*)d_in[2];
    const float* Wn = (const float*)d_in[3];  const float* bn = (const float*)d_in[4];
    const float* We = (const float*)d_in[5];  const float* be = (const float*)d_in[6];
    const float* Wq = (const float*)d_in[7];  const float* bq = (const float*)d_in[8];
    const float* Wk = (const float*)d_in[9];  const float* bk = (const float*)d_in[10];
    const float* Wv = (const float*)d_in[11]; const float* bv = (const float*)d_in[12];
    const float* Wo = (const float*)d_in[13]; const float* bo = (const float*)d_in[14];
    const float* W1 = (const float*)d_in[15]; const float* b1 = (const float*)d_in[16];
    const float* W2 = (const float*)d_in[17]; const float* b2 = (const float*)d_in[18];
    const float* g1 = (const float*)d_in[19]; const float* be1 = (const float*)d_in[20];
    const float* g2 = (const float*)d_in[21]; const float* be2 = (const float*)d_in[22];
    float* out = (float*)d_out;

    // workspace carve (bytes, 256-aligned)
    char* base = (char*)d_ws;
    size_t off = 0;
    auto carve = [&](size_t bytes) { void* p = base + off; off = (off + bytes + 255) & ~(size_t)255; return p; };
    float*  h    = (float*)carve((size_t)NN * HH * 4);
    ushort* hb   = (ushort*)carve((size_t)NN * HH * 2);
    // [po, ff1b, qb, kbf] contiguous 16 MB -> aliased as lastE during setup;
    // [po, ff1b] = 12 MB -> aliased as opart (3 x 4 MB) during attention
    float*  po   = (float*)carve((size_t)NN * HH * 4);
    ushort* ff1b = (ushort*)carve((size_t)NN * 4 * HH * 2);
    ushort* qb   = (ushort*)carve((size_t)NN * HH * 2);
    ushort* kbf  = (ushort*)carve((size_t)NN * HH * 2);
    ushort* vtb  = (ushort*)carve((size_t)NN * HH * 2);
    ushort* aob  = (ushort*)carve((size_t)NN * HH * 2);
    ushort* xb   = (ushort*)carve((size_t)NN * NF_ * 2);
    ushort* WnT  = (ushort*)carve((size_t)HH * NF_ * 2);
    ushort* WqkvT= (ushort*)carve((size_t)3 * HH * HH * 2);
    ushort* WoT  = (ushort*)carve((size_t)HH * HH * 2);
    ushort* W1T  = (ushort*)carve((size_t)4 * HH * HH * 2);
    ushort* W2T  = (ushort*)carve((size_t)4 * HH * HH * 2);
    float*  bqkv = (float*)carve((size_t)3 * HH * 4);
    float*  eb   = (float*)carve((size_t)EE * NHH * 4);
    float*  csr_b= (float*)carve((size_t)EE * NHH * 4);
    float*  Mp   = (float*)carve((size_t)KSPLIT * NHH * NN * 4);
    float*  Sp   = (float*)carve((size_t)KSPLIT * NHH * NN * 4);
    int* cnt     = (int*)carve((size_t)NN * 4);
    int* rowptr  = (int*)carve((size_t)(NN + 1) * 4);
    int* csr_dst = (int*)carve((size_t)EE * 4);
    int* cnt2    = (int*)carve((size_t)NN * NTILE_TOT * 4);
    int* rtptr   = (int*)carve((size_t)(NN * NTILE_TOT + 1) * 4);
    int* rtoff   = (int*)carve((size_t)NN * NTILE_TOT * 4);
    int* lastE = (int*)po;            // setup alias (po+ff1b+qb+kbf = 16 MB)
    float* opart = (float*)po;        // attention partials alias po+ff1b (12 MB)

    // ---- setup
    hipMemsetAsync(lastE, 0xFF, (size_t)NN * NN * 4, stream);
    hipMemsetAsync(cnt, 0, (size_t)NN * 4, stream);
    hipMemsetAsync(cnt2, 0, (size_t)NN * NTILE_TOT * 4, stream);

    xcvt<<<(NN * NF_ + 255) / 256, 256, 0, stream>>>(x, xb, NN * NF_);
    wtrans<<<dim3(HH / 32, NF_ / 32), 256, 0, stream>>>(Wn, WnT, NF_, HH, 0);
    wtrans<<<dim3(HH / 32, HH / 32), 256, 0, stream>>>(Wq, WqkvT, HH, HH, 0);
    wtrans<<<dim3(HH / 32, HH / 32), 256, 0, stream>>>(Wk, WqkvT, HH, HH, 512);
    wtrans<<<dim3(HH / 32, HH / 32), 256, 0, stream>>>(Wv, WqkvT, HH, HH, 1024);
    wtrans<<<dim3(HH / 32, HH / 32), 256, 0, stream>>>(Wo, WoT, HH, HH, 0);
    wtrans<<<dim3(4 * HH / 32, HH / 32), 256, 0, stream>>>(W1, W1T, HH, 4 * HH, 0);
    wtrans<<<dim3(HH / 32, 4 * HH / 32), 256, 0, stream>>>(W2, W2T, 4 * HH, HH, 0);
    bconcat<<<6, 256, 0, stream>>>(bq, bk, bv, bqkv);

    ebias_kernel<<<EE / 256, 256, 0, stream>>>(ea, We, be, eb);
    amax_kernel<<<EE / 256, 256, 0, stream>>>(eidx, lastE);
    count_kernel<<<EE / 256, 256, 0, stream>>>(eidx, lastE, cnt);
    scan2048<<<1, 256, 0, stream>>>(cnt, rowptr);
    rt_count<<<EE / 256, 256, 0, stream>>>(eidx, lastE, cnt2);
    rt_scan<<<NN / 256, 256, 0, stream>>>(rowptr, cnt2, rtptr, rtoff);
    rt_fill<<<EE / 256, 256, 0, stream>>>(eidx, lastE, eb, rtoff, csr_dst, csr_b);

    // h = x @ Wn + bn  (f32 + bf16)
    gemm_mfma<64, 64, 1, 0><<<dim3(HH / 64, NN / 64), 256, 0, stream>>>(
        xb, WnT, bn, h, hb, nullptr, nullptr, nullptr, NN, HH, NF_);

    // ---- transformer layers (GEMM tile A/B: even layers BN=64, odd layers BN=128)
    for (int d = 0; d < DEPTH; ++d) {
        if (d & 1) {
            gemm_mfma<64, 128, 3, 0><<<dim3(3 * HH / 128, NN / 64), 256, 0, stream>>>(
                hb, WqkvT, bqkv, nullptr, nullptr, qb, kbf, vtb, NN, 3 * HH, HH);
        } else {
            gemm_mfma<64, 64, 3, 0><<<dim3(3 * HH / 64, NN / 64), 256, 0, stream>>>(
                hb, WqkvT, bqkv, nullptr, nullptr, qb, kbf, vtb, NN, 3 * HH, HH);
        }
        attn_mfma<<<dim3(32 * NHH * KSPLIT), 256, 0, stream>>>(
            qb, kbf, vtb, rtptr, csr_dst, csr_b, opart, Mp, Sp);
        attn_combine<<<NN * HH / 256, 256, 0, stream>>>(opart, Mp, Sp, aob);
        gemm_mfma<32, 64, 0, 0><<<dim3(HH / 64, NN / 32), 256, 0, stream>>>(
            aob, WoT, bo, po, nullptr, nullptr, nullptr, nullptr, NN, HH, HH);
        ln_kernel<1><<<NN / 4, 256, 0, stream>>>(h, po, g1, be1, h, hb);
        if (d & 1) {
            gemm_mfma<64, 128, 2, 1><<<dim3(4 * HH / 128, NN / 64), 256, 0, stream>>>(
                hb, W1T, b1, nullptr, ff1b, nullptr, nullptr, nullptr, NN, 4 * HH, HH);
        } else {
            gemm_mfma<64, 64, 2, 1><<<dim3(4 * HH / 64, NN / 64), 256, 0, stream>>>(
                hb, W1T, b1, nullptr, ff1b, nullptr, nullptr, nullptr, NN, 4 * HH, HH);
        }
        gemm_mfma<32, 64, 0, 0><<<dim3(HH / 64, NN / 32), 256, 0, stream>>>(
            ff1b, W2T, b2, po, nullptr, nullptr, nullptr, nullptr, NN, HH, 4 * HH);
        float* dst = (d == DEPTH - 1) ? out : h;
        ln_kernel<1><<<NN / 4, 256, 0, stream>>>(h, po, g2, be2, dst, hb);
    }
    (void)in_sizes; (void)n_in; (void)out_size; (void)ws_size;
}

// Round 13
// 562.265 us; speedup vs baseline: 1.3265x; 1.0224x over previous
//
#include <hip/hip_runtime.h>
#include <hip/hip_bf16.h>

// Problem constants (fixed shapes)
#define NN 2048      // nodes
#define EE 65536     // edges
#define NF_ 128
#define HH 512
#define NHH 8
#define HD 64
#define DEPTH 5
#define KSPLIT 3
#define NTILE_TOT (NN / 64)      // 32
#define LOG2E 1.4426950408889634f
#define QSCALE 0.18033688011112042f   // 0.125 * log2e, folded into Q at projection

typedef __attribute__((ext_vector_type(8))) short bf16x8;
typedef __attribute__((ext_vector_type(4))) float f32x4;

__device__ __forceinline__ ushort f2bf(float x) {
    uint u = __builtin_bit_cast(uint, x);
    u += 0x7fffu + ((u >> 16) & 1u);
    return (ushort)(u >> 16);
}

#define GLD16(gp, lp)                                                          \
    __builtin_amdgcn_global_load_lds(                                          \
        (const __attribute__((address_space(1))) unsigned int*)(gp),           \
        (__attribute__((address_space(3))) unsigned int*)(lp), 16, 0, 0)

// ---------------- bf16 MFMA GEMM: C = A[M,K] @ Bt[N,K]^T + bias
// OUT: 0 = f32 C; 1 = f32 C + bf16 Cb; 2 = bf16 Cb; 3 = qkv scatter (Q pre-scaled by QSCALE)
template<int BM, int BN, int OUT, int RELU>
__global__ __launch_bounds__(256) void gemm_mfma(const ushort* __restrict__ A,
                                                 const ushort* __restrict__ Bt,
                                                 const float* __restrict__ bias,
                                                 float* __restrict__ C,
                                                 ushort* __restrict__ Cb,
                                                 ushort* __restrict__ qb,
                                                 ushort* __restrict__ kb,
                                                 ushort* __restrict__ vtb,
                                                 int M, int N, int K) {
    constexpr int WM = BM / 2, WN = BN / 2;
    constexpr int MR = BM / 32, NR = BN / 32;
    __shared__ __align__(16) ushort As[2][BM * 64];
    __shared__ __align__(16) ushort Bs[2][BN * 64];
    const int t = threadIdx.x;
    const int w = t >> 6, l = t & 63;
    const int wr = w >> 1, wc = w & 1;
    const int m0 = blockIdx.y * BM, n0 = blockIdx.x * BN;

    f32x4 acc[MR][NR];
#pragma unroll
    for (int m = 0; m < MR; ++m)
#pragma unroll
        for (int n = 0; n < NR; ++n) acc[m][n] = (f32x4){0.f, 0.f, 0.f, 0.f};

    const int srow = t >> 3, sch = t & 7;
    auto stage = [&](int buf, int kt) {
#pragma unroll
        for (int r = 0; r < MR; ++r) {
            int rr = r * 32 + srow;
            int c = sch ^ (rr & 7);                   // inverse swizzle on SOURCE
            GLD16(A + (size_t)(m0 + rr) * K + kt * 64 + c * 8,
                  &As[buf][rr * 64 + sch * 8]);       // linear LDS dest
        }
#pragma unroll
        for (int r = 0; r < NR; ++r) {
            int rr = r * 32 + srow;
            int c = sch ^ (rr & 7);
            GLD16(Bt + (size_t)(n0 + rr) * K + kt * 64 + c * 8,
                  &Bs[buf][rr * 64 + sch * 8]);
        }
    };

    stage(0, 0);
    const int NT = K / 64;
    for (int kt = 0; kt < NT; ++kt) {
        __syncthreads();
        if (kt + 1 < NT) stage((kt + 1) & 1, kt + 1);
        const int buf = kt & 1;
#pragma unroll
        for (int kk = 0; kk < 2; ++kk) {
            bf16x8 af[MR], bfr[NR];
#pragma unroll
            for (int m = 0; m < MR; ++m) {
                int R = wr * WM + m * 16 + (l & 15);
                int c = kk * 4 + (l >> 4);
                af[m] = *(const bf16x8*)&As[buf][R * 64 + (c ^ (R & 7)) * 8];  // swizzled read
            }
#pragma unroll
            for (int n = 0; n < NR; ++n) {
                int R = wc * WN + n * 16 + (l & 15);
                int c = kk * 4 + (l >> 4);
                bfr[n] = *(const bf16x8*)&Bs[buf][R * 64 + (c ^ (R & 7)) * 8];
            }
#pragma unroll
            for (int m = 0; m < MR; ++m)
#pragma unroll
                for (int n = 0; n < NR; ++n)
                    acc[m][n] = __builtin_amdgcn_mfma_f32_16x16x32_bf16(af[m], bfr[n], acc[m][n], 0, 0, 0);
        }
    }

    // epilogue: C/D layout col=l&15, row=(l>>4)*4+j
#pragma unroll
    for (int m = 0; m < MR; ++m) {
        int row = m0 + wr * WM + m * 16 + (l >> 4) * 4;
#pragma unroll
        for (int n = 0; n < NR; ++n) {
            int col = n0 + wc * WN + n * 16 + (l & 15);
            float bv = bias[col];
            float v4[4];
#pragma unroll
            for (int j = 0; j < 4; ++j) {
                float vv = acc[m][n][j] + bv;
                if (RELU) vv = fmaxf(vv, 0.f);
                v4[j] = vv;
            }
            if (OUT == 0) {
#pragma unroll
                for (int j = 0; j < 4; ++j) C[(size_t)(row + j) * N + col] = v4[j];
            } else if (OUT == 1) {
#pragma unroll
                for (int j = 0; j < 4; ++j) {
                    C[(size_t)(row + j) * N + col] = v4[j];
                    Cb[(size_t)(row + j) * N + col] = f2bf(v4[j]);
                }
            } else if (OUT == 2) {
#pragma unroll
                for (int j = 0; j < 4; ++j) Cb[(size_t)(row + j) * N + col] = f2bf(v4[j]);
            } else {
                int type = col >> 9, head = (col >> 6) & 7, dd = col & 63;
                if (type == 2) {
                    // packed transposed V store: 4 consecutive rows -> one 8B store
                    uint2 pk2;
                    pk2.x = (uint)f2bf(v4[0]) | ((uint)f2bf(v4[1]) << 16);
                    pk2.y = (uint)f2bf(v4[2]) | ((uint)f2bf(v4[3]) << 16);
                    *(uint2*)&vtb[((size_t)head * 64 + dd) * NN + row] = pk2;
                } else if (type == 0) {
#pragma unroll
                    for (int j = 0; j < 4; ++j)
                        qb[((size_t)head * NN + row + j) * 64 + dd] = f2bf(v4[j] * QSCALE);
                } else {
#pragma unroll
                    for (int j = 0; j < 4; ++j)
                        kb[((size_t)head * NN + row + j) * 64 + dd] = f2bf(v4[j]);
                }
            }
        }
    }
}

// ---------------- setup converts
__global__ __launch_bounds__(256) void xcvt(const float* __restrict__ x, ushort* __restrict__ xb, int n) {
    int i = blockIdx.x * 256 + threadIdx.x;
    if (i < n) xb[i] = f2bf(x[i]);
}

__global__ __launch_bounds__(256) void wtrans(const float* __restrict__ W, ushort* __restrict__ WT,
                                              int K, int N, int rowoff) {
    __shared__ float tile[32][33];
    int n0 = blockIdx.x * 32, k0 = blockIdx.y * 32;
    int tc = threadIdx.x & 31, tr = threadIdx.x >> 5;
#pragma unroll
    for (int i = 0; i < 32; i += 8) tile[tr + i][tc] = W[(size_t)(k0 + tr + i) * N + n0 + tc];
    __syncthreads();
#pragma unroll
    for (int i = 0; i < 32; i += 8)
        WT[(size_t)(rowoff + n0 + tr + i) * K + k0 + tc] = f2bf(tile[tc][tr + i]);
}

__global__ __launch_bounds__(256) void bconcat(const float* __restrict__ a, const float* __restrict__ b,
                                               const float* __restrict__ c, float* __restrict__ o) {
    int i = blockIdx.x * 256 + threadIdx.x;
    if (i < 1536) o[i] = i < 512 ? a[i] : (i < 1024 ? b[i - 512] : c[i - 1024]);
}

// ---------------- e_bias = edge_attr @ We + be
__global__ __launch_bounds__(256) void ebias_kernel(const float* __restrict__ ea,
                                                    const float* __restrict__ We,
                                                    const float* __restrict__ be,
                                                    float* __restrict__ eb) {
    int e = blockIdx.x * 256 + threadIdx.x;
    float a[16];
#pragma unroll
    for (int i = 0; i < 16; ++i) a[i] = ea[(size_t)e * 16 + i];
#pragma unroll
    for (int j = 0; j < 8; ++j) {
        float s = be[j];
#pragma unroll
        for (int i = 0; i < 16; ++i) s += a[i] * We[i * 8 + j];
        eb[(size_t)e * 8 + j] = s;
    }
}

// ---------------- dedupe: last edge index wins per (src,dst)
__global__ __launch_bounds__(256) void amax_kernel(const int* __restrict__ eidx, int* __restrict__ lastE) {
    int e = blockIdx.x * 256 + threadIdx.x;
    int s = eidx[e], d = eidx[EE + e];
    atomicMax(&lastE[s * NN + d], e);
}

// ---------------- (row, key-tile) bucketing of bias entries (layer-invariant)
__global__ __launch_bounds__(256) void rt_count(const int* __restrict__ eidx,
                                                const int* __restrict__ lastE,
                                                int* __restrict__ cnt2) {
    int e = blockIdx.x * 256 + threadIdx.x;
    int s = eidx[e], d = eidx[EE + e];
    if (lastE[s * NN + d] == e) atomicAdd(&cnt2[s * NTILE_TOT + (d >> 6)], 1);
}

// per-row totals (atomic-free)
__global__ __launch_bounds__(256) void rowsum_kernel(const int* __restrict__ cnt2,
                                                     int* __restrict__ cnt) {
    int row = blockIdx.x * 256 + threadIdx.x;
    if (row >= NN) return;
    int s = 0;
#pragma unroll
    for (int t = 0; t < NTILE_TOT; ++t) s += cnt2[row * NTILE_TOT + t];
    cnt[row] = s;
}

__global__ __launch_bounds__(256) void scan2048(const int* __restrict__ cnt,
                                                int* __restrict__ rowptr) {
    __shared__ int sums[256];
    int t = threadIdx.x;
    int loc[8];
    int s = 0;
#pragma unroll
    for (int i = 0; i < 8; ++i) { loc[i] = s; s += cnt[t * 8 + i]; }
    sums[t] = s;
    __syncthreads();
    for (int off = 1; off < 256; off <<= 1) {
        int v = (t >= off) ? sums[t - off] : 0;
        __syncthreads();
        sums[t] += v;
        __syncthreads();
    }
    int base = (t == 0) ? 0 : sums[t - 1];
#pragma unroll
    for (int i = 0; i < 8; ++i) rowptr[t * 8 + i] = base + loc[i];
    if (t == 255) rowptr[NN] = sums[255];
}

__global__ __launch_bounds__(256) void rt_scan(const int* __restrict__ rowptr,
                                               const int* __restrict__ cnt2,
                                               int* __restrict__ rtptr,
                                               int* __restrict__ rtoff) {
    int row = blockIdx.x * 256 + threadIdx.x;
    if (row >= NN) return;
    int base = rowptr[row];
#pragma unroll
    for (int t = 0; t < NTILE_TOT; ++t) {
        rtptr[row * NTILE_TOT + t] = base;
        rtoff[row * NTILE_TOT + t] = base;
        base += cnt2[row * NTILE_TOT + t];
    }
    if (row == NN - 1) rtptr[NN * NTILE_TOT] = base;
}

// fill buckets: dst stored relative to tile (0..63); bias pre-scaled by log2e
__global__ __launch_bounds__(256) void rt_fill(const int* __restrict__ eidx,
                                               const int* __restrict__ lastE,
                                               const float* __restrict__ eb,
                                               int* __restrict__ rtoff,
                                               int* __restrict__ csr_dst,
                                               float* __restrict__ csr_b) {
    int e = blockIdx.x * 256 + threadIdx.x;
    int s = eidx[e], d = eidx[EE + e];
    if (lastE[s * NN + d] == e) {
        int pos = atomicAdd(&rtoff[s * NTILE_TOT + (d >> 6)], 1);
        csr_dst[pos] = d & 63;
#pragma unroll
        for (int j = 0; j < 8; ++j) csr_b[(size_t)pos * 8 + j] = eb[(size_t)e * 8 + j] * LOG2E;
    }
}

// ---------------- split-K flash attention (round-12 structure, BIASLDS=1)
// grid 768 = qblk(32) x head(8) x ks(3), XCD-chunk swizzled. 1 barrier/tile.
__global__ __launch_bounds__(256) void attn_mfma(const ushort* __restrict__ qb,
                                                 const ushort* __restrict__ kb,
                                                 const ushort* __restrict__ vtb,
                                                 const int* __restrict__ rtptr,
                                                 const int* __restrict__ csr_dst,
                                                 const float* __restrict__ csr_b,
                                                 float* __restrict__ opart,
                                                 float* __restrict__ Mp,
                                                 float* __restrict__ Sp) {
    const int id = blockIdx.x;
    const int f = (id & 7) * 96 + (id >> 3);    // 768 blocks, 96/XCD
    const int n0 = (f & 31) * 64;
    const int head = (f >> 5) & 7;
    const int ks = f >> 8;                       // 0..2
    const int tstart = (ks * 32) / 3, tend = ((ks + 1) * 32) / 3;   // 10/11/11 tiles
    const int t = threadIdx.x;
    const int w = t >> 6, l = t & 63;
    const int lq = l & 15, lg = l >> 4;

    __shared__ __align__(16) ushort Ks2[2][64 * 64];   // K dbuf, swizzled
    __shared__ __align__(16) ushort Vs2[2][64 * 64];   // V dbuf, swizzled
    __shared__ __align__(16) ushort Bb[4][16 * 72];    // per-wave bias mini-tile (bf16)
    __shared__ int Rt[64][12];                         // bucket bounds per block row

    // persistent Q fragments (pre-scaled by QSCALE): rows n0 + w*16 + lq
    bf16x8 qf0, qf1;
    {
        int r = n0 + w * 16 + lq;
        const ushort* qp = qb + ((size_t)head * NN + r) * HD + lg * 8;
        qf0 = *(const bf16x8*)qp;
        qf1 = *(const bf16x8*)(qp + 32);
    }
    const int ntile = tend - tstart;
    for (int i = t; i < 64 * 12; i += 256) {
        int r = i / 12, c = i % 12;
        if (c <= ntile) Rt[r][c] = rtptr[(n0 + r) * NTILE_TOT + tstart + c];
    }
    float M = -1e30f, S = 0.f;
    f32x4 o[4];
#pragma unroll
    for (int db = 0; db < 4; ++db) o[db] = (f32x4){0.f, 0.f, 0.f, 0.f};

    auto stageK = [&](int buf, int tile) {
        int m0k = tile * 64;
#pragma unroll
        for (int s = 0; s < 2; ++s) {
            int slot = t + s * 256;
            int rr = slot >> 3, blk = slot & 7, sb = blk ^ (rr & 7);
            GLD16(kb + ((size_t)head * NN + m0k + rr) * 64 + sb * 8,
                  &Ks2[buf][rr * 64 + blk * 8]);
        }
    };
    auto stageV = [&](int buf, int tile) {
        int m0k = tile * 64;
#pragma unroll
        for (int s = 0; s < 2; ++s) {
            int slot = t + s * 256;
            int rr = slot >> 3, blk = slot & 7, sb = blk ^ (rr & 7);
            GLD16(vtb + ((size_t)head * 64 + rr) * NN + m0k + sb * 8,
                  &Vs2[buf][rr * 64 + blk * 8]);
        }
    };

    stageK(0, tstart);
    stageV(0, tstart);
    __syncthreads();   // tile 0 landed, Rt visible

    // P lane-exchange constants (dest lane lg pulls from src lane ((2lg+c)&3)*16+lq)
    const int sl0 = (((lg << 1) + 0) & 3) * 16 + lq;
    const int sl1 = (((lg << 1) + 1) & 3) * 16 + lq;
    const int hi = lg & 2;

    for (int tt = tstart; tt < tend; ++tt) {
        const int tl = tt - tstart;
        const int cb = tl & 1;
        if (tt + 1 < tend) { stageK(cb ^ 1, tt + 1); stageV(cb ^ 1, tt + 1); }

        const int rq = w * 16 + lq;
        const int p0 = Rt[rq][tl], p1 = Rt[rq][tl + 1];

        // zero this wave's bias mini-tile (wave-coherent, no barrier needed)
        for (int i = l; i < 144; i += 64)
            *(uint4*)&Bb[w][i * 8] = (uint4){0, 0, 0, 0};
        // scatter bucket entries (lg==0 lanes only; ~1 entry/row avg)
        if (lg == 0) {
            for (int e = p0; e < p1; ++e)
                Bb[w][lq * 72 + csr_dst[e]] = f2bf(csr_b[(size_t)e * 8 + head]);
        }

        // ---- QK^T (swapped): vv[b][j] = score[q=lq][key = b*16 + lg*4 + j]
        f32x4 vv[4];
        {
            const ushort* Kb_ = &Ks2[cb][0];
            __builtin_amdgcn_s_setprio(1);
#pragma unroll
            for (int b = 0; b < 4; ++b) {
                int key = b * 16 + lq;
                bf16x8 k0 = *(const bf16x8*)&Kb_[key * 64 + ((lg ^ (key & 7)) * 8)];
                bf16x8 k1 = *(const bf16x8*)&Kb_[key * 64 + (((lg + 4) ^ (key & 7)) * 8)];
                f32x4 s_ = {0.f, 0.f, 0.f, 0.f};
                s_ = __builtin_amdgcn_mfma_f32_16x16x32_bf16(k0, qf0, s_, 0, 0, 0);
                s_ = __builtin_amdgcn_mfma_f32_16x16x32_bf16(k1, qf1, s_, 0, 0, 0);
                vv[b] = s_;
            }
            __builtin_amdgcn_s_setprio(0);
        }

        // ---- bias merge from mini-tile
#pragma unroll
        for (int b = 0; b < 4; ++b) {
            uint2 bb = *(const uint2*)&Bb[w][lq * 72 + b * 16 + lg * 4];
            vv[b][0] += __builtin_bit_cast(float, bb.x << 16);
            vv[b][1] += __builtin_bit_cast(float, bb.x & 0xffff0000u);
            vv[b][2] += __builtin_bit_cast(float, bb.y << 16);
            vv[b][3] += __builtin_bit_cast(float, bb.y & 0xffff0000u);
        }

        // ---- wave-local online softmax (log2 space), exact defer-rescale
        float mx = vv[0][0];
#pragma unroll
        for (int b = 0; b < 4; ++b)
#pragma unroll
            for (int j = 0; j < 4; ++j) mx = fmaxf(mx, vv[b][j]);
        mx = fmaxf(mx, __shfl_xor(mx, 16, 64));
        mx = fmaxf(mx, __shfl_xor(mx, 32, 64));
        if (!__all(mx <= M)) {
            float Mn = fmaxf(M, mx);
            float fr = exp2f(M - Mn);
            M = Mn;
            S *= fr;
#pragma unroll
            for (int j = 0; j < 4; ++j) {
                float Fj = __shfl(fr, lg * 4 + j, 64);
                o[0][j] *= Fj; o[1][j] *= Fj; o[2][j] *= Fj; o[3][j] *= Fj;
            }
        }
        float ts = 0.f;
#pragma unroll
        for (int b = 0; b < 4; ++b)
#pragma unroll
            for (int j = 0; j < 4; ++j) { vv[b][j] = exp2f(vv[b][j] - M); ts += vv[b][j]; }
        ts += __shfl_xor(ts, 16, 64);
        ts += __shfl_xor(ts, 32, 64);
        S += ts;

        // ---- pack P: U[2b+p] = bf16pair(vv[b][2p], vv[b][2p+1]) via v_cvt_pk
        uint U0, U1, U2, U3, U4, U5, U6, U7;
        asm("v_cvt_pk_bf16_f32 %0, %1, %2" : "=v"(U0) : "v"(vv[0][0]), "v"(vv[0][1]));
        asm("v_cvt_pk_bf16_f32 %0, %1, %2" : "=v"(U1) : "v"(vv[0][2]), "v"(vv[0][3]));
        asm("v_cvt_pk_bf16_f32 %0, %1, %2" : "=v"(U2) : "v"(vv[1][0]), "v"(vv[1][1]));
        asm("v_cvt_pk_bf16_f32 %0, %1, %2" : "=v"(U3) : "v"(vv[1][2]), "v"(vv[1][3]));
        asm("v_cvt_pk_bf16_f32 %0, %1, %2" : "=v"(U4) : "v"(vv[2][0]), "v"(vv[2][1]));
        asm("v_cvt_pk_bf16_f32 %0, %1, %2" : "=v"(U5) : "v"(vv[2][2]), "v"(vv[2][3]));
        asm("v_cvt_pk_bf16_f32 %0, %1, %2" : "=v"(U6) : "v"(vv[3][0]), "v"(vv[3][1]));
        asm("v_cvt_pk_bf16_f32 %0, %1, %2" : "=v"(U7) : "v"(vv[3][2]), "v"(vv[3][3]));

        // ---- in-register P exchange: pa0 = P[lq][keys lg*8..+7], pa1 = keys 32+lg*8..+7
        uint ra, rb;
        ra = (uint)__shfl((int)U0, sl0); rb = (uint)__shfl((int)U2, sl0);
        uint p00 = hi ? rb : ra;
        ra = (uint)__shfl((int)U1, sl0); rb = (uint)__shfl((int)U3, sl0);
        uint p01 = hi ? rb : ra;
        ra = (uint)__shfl((int)U0, sl1); rb = (uint)__shfl((int)U2, sl1);
        uint p02 = hi ? rb : ra;
        ra = (uint)__shfl((int)U1, sl1); rb = (uint)__shfl((int)U3, sl1);
        uint p03 = hi ? rb : ra;
        ra = (uint)__shfl((int)U4, sl0); rb = (uint)__shfl((int)U6, sl0);
        uint p10 = hi ? rb : ra;
        ra = (uint)__shfl((int)U5, sl0); rb = (uint)__shfl((int)U7, sl0);
        uint p11 = hi ? rb : ra;
        ra = (uint)__shfl((int)U4, sl1); rb = (uint)__shfl((int)U6, sl1);
        uint p12 = hi ? rb : ra;
        ra = (uint)__shfl((int)U5, sl1); rb = (uint)__shfl((int)U7, sl1);
        uint p13 = hi ? rb : ra;
        uint4 pu0 = {p00, p01, p02, p03};
        uint4 pu1 = {p10, p11, p12, p13};
        bf16x8 pa0 = __builtin_bit_cast(bf16x8, pu0);
        bf16x8 pa1 = __builtin_bit_cast(bf16x8, pu1);

        // ---- PV: A = P (in-register), B = V^T from LDS
        {
            const ushort* Vb_ = &Vs2[cb][0];
            __builtin_amdgcn_s_setprio(1);
#pragma unroll
            for (int db = 0; db < 4; ++db) {
                int dim = db * 16 + lq;
                bf16x8 v0 = *(const bf16x8*)&Vb_[dim * 64 + ((lg ^ (dim & 7)) * 8)];
                bf16x8 v1 = *(const bf16x8*)&Vb_[dim * 64 + (((lg + 4) ^ (dim & 7)) * 8)];
                o[db] = __builtin_amdgcn_mfma_f32_16x16x32_bf16(pa0, v0, o[db], 0, 0, 0);
                o[db] = __builtin_amdgcn_mfma_f32_16x16x32_bf16(pa1, v1, o[db], 0, 0, 0);
            }
            __builtin_amdgcn_s_setprio(0);
        }
        __syncthreads();   // next-tile stage landed; buffers free for reuse
    }

    // ---- write partials: o[db][j] is row n0+w*16+lg*4+j, dim db*16+lq
#pragma unroll
    for (int db = 0; db < 4; ++db)
#pragma unroll
        for (int j = 0; j < 4; ++j) {
            int r = n0 + w * 16 + lg * 4 + j;
            opart[((size_t)ks * NN + r) * HH + head * HD + db * 16 + lq] = o[db][j];
        }
    if (l < 16) {
        int r = n0 + w * 16 + l;
        Mp[((size_t)ks * NHH + head) * NN + r] = M;
        Sp[((size_t)ks * NHH + head) * NN + r] = S;
    }
}

// combine 3 partials -> bf16 attention output (log2-space M)
__global__ __launch_bounds__(256) void attn_combine(const float* __restrict__ opart,
                                                    const float* __restrict__ Mp,
                                                    const float* __restrict__ Sp,
                                                    ushort* __restrict__ aob) {
    int i = blockIdx.x * 256 + threadIdx.x;
    int row = i >> 9, col = i & 511;
    int head = col >> 6;
    float m0 = Mp[(size_t)head * NN + row];
    float m1 = Mp[((size_t)NHH + head) * NN + row];
    float m2 = Mp[((size_t)2 * NHH + head) * NN + row];
    float s0 = Sp[(size_t)head * NN + row];
    float s1 = Sp[((size_t)NHH + head) * NN + row];
    float s2 = Sp[((size_t)2 * NHH + head) * NN + row];
    float m = fmaxf(m0, fmaxf(m1, m2));
    float w0 = exp2f(m0 - m), w1 = exp2f(m1 - m), w2 = exp2f(m2 - m);
    float num = opart[(size_t)row * HH + col] * w0
              + opart[((size_t)NN + row) * HH + col] * w1
              + opart[((size_t)2 * NN + row) * HH + col] * w2;
    float den = s0 * w0 + s1 * w1 + s2 * w2;
    aob[i] = f2bf(num / den);
}

// ---------------- LayerNorm(out = LN(a + b) * g + be); optional bf16 copy
template<int BF16OUT>
__global__ __launch_bounds__(256) void ln_kernel(const float* __restrict__ a,
                                                 const float* __restrict__ b,
                                                 const float* __restrict__ g,
                                                 const float* __restrict__ be,
                                                 float* __restrict__ out,
                                                 ushort* __restrict__ outb) {
    int row = blockIdx.x * 4 + (threadIdx.x >> 6);
    int lane = threadIdx.x & 63;
    const float* pa = a + (size_t)row * HH;
    const float* pb = b + (size_t)row * HH;
    float x[8];
    float s = 0.f;
#pragma unroll
    for (int i = 0; i < 8; ++i) { x[i] = pa[lane + i * 64] + pb[lane + i * 64]; s += x[i]; }
#pragma unroll
    for (int off = 32; off > 0; off >>= 1) s += __shfl_xor(s, off, 64);
    float mean = s * (1.f / 512.f);
    float vs = 0.f;
#pragma unroll
    for (int i = 0; i < 8; ++i) { float d = x[i] - mean; vs += d * d; }
#pragma unroll
    for (int off = 32; off > 0; off >>= 1) vs += __shfl_xor(vs, off, 64);
    float rs = rsqrtf(vs * (1.f / 512.f) + 1e-5f);
    float* po = out + (size_t)row * HH;
    ushort* pob = outb + (size_t)row * HH;
#pragma unroll
    for (int i = 0; i < 8; ++i) {
        float v = (x[i] - mean) * rs * g[lane + i * 64] + be[lane + i * 64];
        po[lane + i * 64] = v;
        if (BF16OUT) pob[lane + i * 64] = f2bf(v);
    }
}

extern "C" void kernel_launch(void* const* d_in, const int* in_sizes, int n_in,
                              void* d_out, int out_size, void* d_ws, size_t ws_size,
                              hipStream_t stream) {
    const float* x   = (const float*)d_in[0];
    const int*  eidx = (const int*)d_in[1];
    const float* ea  = (const float*)d_in[2];
    const float* Wn = (const float*)d_in[3];  const float* bn = (const float*)d_in[4];
    const float* We = (const float*)d_in[5];  const float* be = (const float*)d_in[6];
    const float* Wq = (const float*)d_in[7];  const float* bq = (const float*)d_in[8];
    const float* Wk = (const float*)d_in[9];  const float* bk = (const float*)d_in[10];
    const float* Wv = (const float*)d_in[11]; const float* bv = (const float*)d_in[12];
    const float* Wo = (const float*)d_in[13]; const float* bo = (const float*)d_in[14];
    const float* W1 = (const float*)d_in[15]; const float* b1 = (const float*)d_in[16];
    const float* W2 = (const float*)d_in[17]; const float* b2 = (const float*)d_in[18];
    const float* g1 = (const float*)d_in[19]; const float* be1 = (const float*)d_in[20];
    const float* g2 = (const float*)d_in[21]; const float* be2 = (const float*)d_in[22];
    float* out = (float*)d_out;

    // workspace carve (bytes, 256-aligned)
    char* base = (char*)d_ws;
    size_t off = 0;
    auto carve = [&](size_t bytes) { void* p = base + off; off = (off + bytes + 255) & ~(size_t)255; return p; };
    float*  h    = (float*)carve((size_t)NN * HH * 4);
    ushort* hb   = (ushort*)carve((size_t)NN * HH * 2);
    // [po, ff1b, qb, kbf] contiguous 16 MB -> aliased as lastE during setup;
    // [po, ff1b] = 12 MB -> aliased as opart (3 x 4 MB) during attention
    float*  po   = (float*)carve((size_t)NN * HH * 4);
    ushort* ff1b = (ushort*)carve((size_t)NN * 4 * HH * 2);
    ushort* qb   = (ushort*)carve((size_t)NN * HH * 2);
    ushort* kbf  = (ushort*)carve((size_t)NN * HH * 2);
    ushort* vtb  = (ushort*)carve((size_t)NN * HH * 2);
    ushort* aob  = (ushort*)carve((size_t)NN * HH * 2);
    ushort* xb   = (ushort*)carve((size_t)NN * NF_ * 2);
    ushort* WnT  = (ushort*)carve((size_t)HH * NF_ * 2);
    ushort* WqkvT= (ushort*)carve((size_t)3 * HH * HH * 2);
    ushort* WoT  = (ushort*)carve((size_t)HH * HH * 2);
    ushort* W1T  = (ushort*)carve((size_t)4 * HH * HH * 2);
    ushort* W2T  = (ushort*)carve((size_t)4 * HH * HH * 2);
    float*  bqkv = (float*)carve((size_t)3 * HH * 4);
    float*  eb   = (float*)carve((size_t)EE * NHH * 4);
    float*  csr_b= (float*)carve((size_t)EE * NHH * 4);
    float*  Mp   = (float*)carve((size_t)KSPLIT * NHH * NN * 4);
    float*  Sp   = (float*)carve((size_t)KSPLIT * NHH * NN * 4);
    int* cnt     = (int*)carve((size_t)NN * 4);
    int* rowptr  = (int*)carve((size_t)(NN + 1) * 4);
    int* csr_dst = (int*)carve((size_t)EE * 4);
    int* cnt2    = (int*)carve((size_t)NN * NTILE_TOT * 4);
    int* rtptr   = (int*)carve((size_t)(NN * NTILE_TOT + 1) * 4);
    int* rtoff   = (int*)carve((size_t)NN * NTILE_TOT * 4);
    int* lastE = (int*)po;            // setup alias (po+ff1b+qb+kbf = 16 MB)
    float* opart = (float*)po;        // attention partials alias po+ff1b (12 MB)

    // ---- setup
    hipMemsetAsync(lastE, 0xFF, (size_t)NN * NN * 4, stream);
    hipMemsetAsync(cnt2, 0, (size_t)NN * NTILE_TOT * 4, stream);

    xcvt<<<(NN * NF_ + 255) / 256, 256, 0, stream>>>(x, xb, NN * NF_);
    wtrans<<<dim3(HH / 32, NF_ / 32), 256, 0, stream>>>(Wn, WnT, NF_, HH, 0);
    wtrans<<<dim3(HH / 32, HH / 32), 256, 0, stream>>>(Wq, WqkvT, HH, HH, 0);
    wtrans<<<dim3(HH / 32, HH / 32), 256, 0, stream>>>(Wk, WqkvT, HH, HH, 512);
    wtrans<<<dim3(HH / 32, HH / 32), 256, 0, stream>>>(Wv, WqkvT, HH, HH, 1024);
    wtrans<<<dim3(HH / 32, HH / 32), 256, 0, stream>>>(Wo, WoT, HH, HH, 0);
    wtrans<<<dim3(4 * HH / 32, HH / 32), 256, 0, stream>>>(W1, W1T, HH, 4 * HH, 0);
    wtrans<<<dim3(HH / 32, 4 * HH / 32), 256, 0, stream>>>(W2, W2T, 4 * HH, HH, 0);
    bconcat<<<6, 256, 0, stream>>>(bq, bk, bv, bqkv);

    ebias_kernel<<<EE / 256, 256, 0, stream>>>(ea, We, be, eb);
    amax_kernel<<<EE / 256, 256, 0, stream>>>(eidx, lastE);
    rt_count<<<EE / 256, 256, 0, stream>>>(eidx, lastE, cnt2);
    rowsum_kernel<<<NN / 256, 256, 0, stream>>>(cnt2, cnt);
    scan2048<<<1, 256, 0, stream>>>(cnt, rowptr);
    rt_scan<<<NN / 256, 256, 0, stream>>>(rowptr, cnt2, rtptr, rtoff);
    rt_fill<<<EE / 256, 256, 0, stream>>>(eidx, lastE, eb, rtoff, csr_dst, csr_b);

    // h = x @ Wn + bn  (f32 + bf16)
    gemm_mfma<64, 64, 1, 0><<<dim3(HH / 64, NN / 64), 256, 0, stream>>>(
        xb, WnT, bn, h, hb, nullptr, nullptr, nullptr, NN, HH, NF_);

    // ---- transformer layers (uniform BN=64 per A/B verdict)
    for (int d = 0; d < DEPTH; ++d) {
        gemm_mfma<64, 64, 3, 0><<<dim3(3 * HH / 64, NN / 64), 256, 0, stream>>>(
            hb, WqkvT, bqkv, nullptr, nullptr, qb, kbf, vtb, NN, 3 * HH, HH);
        attn_mfma<<<dim3(32 * NHH * KSPLIT), 256, 0, stream>>>(
            qb, kbf, vtb, rtptr, csr_dst, csr_b, opart, Mp, Sp);
        attn_combine<<<NN * HH / 256, 256, 0, stream>>>(opart, Mp, Sp, aob);
        gemm_mfma<32, 64, 0, 0><<<dim3(HH / 64, NN / 32), 256, 0, stream>>>(
            aob, WoT, bo, po, nullptr, nullptr, nullptr, nullptr, NN, HH, HH);
        ln_kernel<1><<<NN / 4, 256, 0, stream>>>(h, po, g1, be1, h, hb);
        gemm_mfma<64, 64, 2, 1><<<dim3(4 * HH / 64, NN / 64), 256, 0, stream>>>(
            hb, W1T, b1, nullptr, ff1b, nullptr, nullptr, nullptr, NN, 4 * HH, HH);
        gemm_mfma<32, 64, 0, 0><<<dim3(HH / 64, NN / 32), 256, 0, stream>>>(
            ff1b, W2T, b2, po, nullptr, nullptr, nullptr, nullptr, NN, HH, 4 * HH);
        float* dst = (d == DEPTH - 1) ? out : h;
        ln_kernel<1><<<NN / 4, 256, 0, stream>>>(h, po, g2, be2, dst, hb);
    }
    (void)in_sizes; (void)n_in; (void)out_size; (void)ws_size;
}

// Round 14
// 557.513 us; speedup vs baseline: 1.3378x; 1.0085x over previous
//
#include <hip/hip_runtime.h>
#include <hip/hip_bf16.h>

// Problem constants (fixed shapes)
#define NN 2048      // nodes
#define EE 65536     // edges
#define NF_ 128
#define HH 512
#define NHH 8
#define HD 64
#define DEPTH 5
#define KSPLIT 3
#define NTILE_TOT (NN / 64)      // 32
#define LOG2E 1.4426950408889634f
#define QSCALE 0.18033688011112042f   // 0.125 * log2e, folded into Q at projection

typedef __attribute__((ext_vector_type(8))) short bf16x8;
typedef __attribute__((ext_vector_type(4))) float f32x4;

__device__ __forceinline__ ushort f2bf(float x) {
    uint u = __builtin_bit_cast(uint, x);
    u += 0x7fffu + ((u >> 16) & 1u);
    return (ushort)(u >> 16);
}

#define GLD16(gp, lp)                                                          \
    __builtin_amdgcn_global_load_lds(                                          \
        (const __attribute__((address_space(1))) unsigned int*)(gp),           \
        (__attribute__((address_space(3))) unsigned int*)(lp), 16, 0, 0)

// ---------------- bf16 MFMA GEMM: C = A[M,K] @ Bt[N,K]^T + bias
// OUT: 0 = f32 C; 1 = f32 C + bf16 Cb; 2 = bf16 Cb; 3 = qkv scatter (Q pre-scaled by QSCALE)
template<int BM, int BN, int OUT, int RELU>
__global__ __launch_bounds__(256) void gemm_mfma(const ushort* __restrict__ A,
                                                 const ushort* __restrict__ Bt,
                                                 const float* __restrict__ bias,
                                                 float* __restrict__ C,
                                                 ushort* __restrict__ Cb,
                                                 ushort* __restrict__ qb,
                                                 ushort* __restrict__ kb,
                                                 ushort* __restrict__ vtb,
                                                 int M, int N, int K) {
    constexpr int WM = BM / 2, WN = BN / 2;
    constexpr int MR = BM / 32, NR = BN / 32;
    __shared__ __align__(16) ushort As[2][BM * 64];
    __shared__ __align__(16) ushort Bs[2][BN * 64];
    const int t = threadIdx.x;
    const int w = t >> 6, l = t & 63;
    const int wr = w >> 1, wc = w & 1;
    const int m0 = blockIdx.y * BM, n0 = blockIdx.x * BN;

    f32x4 acc[MR][NR];
#pragma unroll
    for (int m = 0; m < MR; ++m)
#pragma unroll
        for (int n = 0; n < NR; ++n) acc[m][n] = (f32x4){0.f, 0.f, 0.f, 0.f};

    const int srow = t >> 3, sch = t & 7;
    auto stage = [&](int buf, int kt) {
#pragma unroll
        for (int r = 0; r < MR; ++r) {
            int rr = r * 32 + srow;
            int c = sch ^ (rr & 7);                   // inverse swizzle on SOURCE
            GLD16(A + (size_t)(m0 + rr) * K + kt * 64 + c * 8,
                  &As[buf][rr * 64 + sch * 8]);       // linear LDS dest
        }
#pragma unroll
        for (int r = 0; r < NR; ++r) {
            int rr = r * 32 + srow;
            int c = sch ^ (rr & 7);
            GLD16(Bt + (size_t)(n0 + rr) * K + kt * 64 + c * 8,
                  &Bs[buf][rr * 64 + sch * 8]);
        }
    };

    stage(0, 0);
    const int NT = K / 64;
    for (int kt = 0; kt < NT; ++kt) {
        __syncthreads();
        if (kt + 1 < NT) stage((kt + 1) & 1, kt + 1);
        const int buf = kt & 1;
#pragma unroll
        for (int kk = 0; kk < 2; ++kk) {
            bf16x8 af[MR], bfr[NR];
#pragma unroll
            for (int m = 0; m < MR; ++m) {
                int R = wr * WM + m * 16 + (l & 15);
                int c = kk * 4 + (l >> 4);
                af[m] = *(const bf16x8*)&As[buf][R * 64 + (c ^ (R & 7)) * 8];  // swizzled read
            }
#pragma unroll
            for (int n = 0; n < NR; ++n) {
                int R = wc * WN + n * 16 + (l & 15);
                int c = kk * 4 + (l >> 4);
                bfr[n] = *(const bf16x8*)&Bs[buf][R * 64 + (c ^ (R & 7)) * 8];
            }
#pragma unroll
            for (int m = 0; m < MR; ++m)
#pragma unroll
                for (int n = 0; n < NR; ++n)
                    acc[m][n] = __builtin_amdgcn_mfma_f32_16x16x32_bf16(af[m], bfr[n], acc[m][n], 0, 0, 0);
        }
    }

    // epilogue: C/D layout col=l&15, row=(l>>4)*4+j
#pragma unroll
    for (int m = 0; m < MR; ++m) {
        int row = m0 + wr * WM + m * 16 + (l >> 4) * 4;
#pragma unroll
        for (int n = 0; n < NR; ++n) {
            int col = n0 + wc * WN + n * 16 + (l & 15);
            float bv = bias[col];
            float v4[4];
#pragma unroll
            for (int j = 0; j < 4; ++j) {
                float vv = acc[m][n][j] + bv;
                if (RELU) vv = fmaxf(vv, 0.f);
                v4[j] = vv;
            }
            if (OUT == 0) {
#pragma unroll
                for (int j = 0; j < 4; ++j) C[(size_t)(row + j) * N + col] = v4[j];
            } else if (OUT == 1) {
#pragma unroll
                for (int j = 0; j < 4; ++j) {
                    C[(size_t)(row + j) * N + col] = v4[j];
                    Cb[(size_t)(row + j) * N + col] = f2bf(v4[j]);
                }
            } else if (OUT == 2) {
#pragma unroll
                for (int j = 0; j < 4; ++j) Cb[(size_t)(row + j) * N + col] = f2bf(v4[j]);
            } else {
                int type = col >> 9, head = (col >> 6) & 7, dd = col & 63;
                if (type == 2) {
                    // packed transposed V store: 4 consecutive rows -> one 8B store
                    uint2 pk2;
                    pk2.x = (uint)f2bf(v4[0]) | ((uint)f2bf(v4[1]) << 16);
                    pk2.y = (uint)f2bf(v4[2]) | ((uint)f2bf(v4[3]) << 16);
                    *(uint2*)&vtb[((size_t)head * 64 + dd) * NN + row] = pk2;
                } else if (type == 0) {
#pragma unroll
                    for (int j = 0; j < 4; ++j)
                        qb[((size_t)head * NN + row + j) * 64 + dd] = f2bf(v4[j] * QSCALE);
                } else {
#pragma unroll
                    for (int j = 0; j < 4; ++j)
                        kb[((size_t)head * NN + row + j) * 64 + dd] = f2bf(v4[j]);
                }
            }
        }
    }
}

// ---------------- merged setup: ebias (blocks 0..255) + xcvt (256..1279) + bconcat (1280)
__global__ __launch_bounds__(256) void setup_misc(const float* __restrict__ ea,
                                                  const float* __restrict__ We,
                                                  const float* __restrict__ be,
                                                  float* __restrict__ eb,
                                                  const float* __restrict__ x,
                                                  ushort* __restrict__ xb,
                                                  const float* __restrict__ bq,
                                                  const float* __restrict__ bk,
                                                  const float* __restrict__ bv,
                                                  float* __restrict__ bqkv) {
    int b = blockIdx.x, t = threadIdx.x;
    if (b < 256) {
        int e = b * 256 + t;
        float a[16];
#pragma unroll
        for (int i = 0; i < 16; ++i) a[i] = ea[(size_t)e * 16 + i];
#pragma unroll
        for (int j = 0; j < 8; ++j) {
            float s = be[j];
#pragma unroll
            for (int i = 0; i < 16; ++i) s += a[i] * We[i * 8 + j];
            eb[(size_t)e * 8 + j] = s;
        }
    } else if (b < 1280) {
        int i = (b - 256) * 256 + t;
        xb[i] = f2bf(x[i]);
    } else {
        for (int i = t; i < 1536; i += 256)
            bqkv[i] = i < 512 ? bq[i] : (i < 1024 ? bk[i - 512] : bv[i - 1024]);
    }
}

// ---------------- merged weight transposes: W[K][N] f32 -> WT[(rowoff+n)][k] bf16
__global__ __launch_bounds__(256) void wtrans_all(const float* __restrict__ Wn,
                                                  const float* __restrict__ Wq,
                                                  const float* __restrict__ Wk,
                                                  const float* __restrict__ Wv,
                                                  const float* __restrict__ Wo,
                                                  const float* __restrict__ W1,
                                                  const float* __restrict__ W2,
                                                  ushort* __restrict__ WnT,
                                                  ushort* __restrict__ WqkvT,
                                                  ushort* __restrict__ WoT,
                                                  ushort* __restrict__ W1T,
                                                  ushort* __restrict__ W2T) {
    int b = blockIdx.x;
    const float* W; ushort* WT; int K, N, rowoff, tid;
    if (b < 64)        { W = Wn; WT = WnT;   K = 128;  N = 512;  rowoff = 0;    tid = b; }
    else if (b < 320)  { W = Wq; WT = WqkvT; K = 512;  N = 512;  rowoff = 0;    tid = b - 64; }
    else if (b < 576)  { W = Wk; WT = WqkvT; K = 512;  N = 512;  rowoff = 512;  tid = b - 320; }
    else if (b < 832)  { W = Wv; WT = WqkvT; K = 512;  N = 512;  rowoff = 1024; tid = b - 576; }
    else if (b < 1088) { W = Wo; WT = WoT;   K = 512;  N = 512;  rowoff = 0;    tid = b - 832; }
    else if (b < 2112) { W = W1; WT = W1T;   K = 512;  N = 2048; rowoff = 0;    tid = b - 1088; }
    else               { W = W2; WT = W2T;   K = 2048; N = 512;  rowoff = 0;    tid = b - 2112; }
    int nt = N / 32;
    int n0 = (tid % nt) * 32, k0 = (tid / nt) * 32;

    __shared__ float tile[32][33];
    int tc = threadIdx.x & 31, tr = threadIdx.x >> 5;
#pragma unroll
    for (int i = 0; i < 32; i += 8) tile[tr + i][tc] = W[(size_t)(k0 + tr + i) * N + n0 + tc];
    __syncthreads();
#pragma unroll
    for (int i = 0; i < 32; i += 8)
        WT[(size_t)(rowoff + n0 + tr + i) * K + k0 + tc] = f2bf(tile[tc][tr + i]);
}

// ---------------- dedupe: last edge index wins per (src,dst)
__global__ __launch_bounds__(256) void amax_kernel(const int* __restrict__ eidx, int* __restrict__ lastE) {
    int e = blockIdx.x * 256 + threadIdx.x;
    int s = eidx[e], d = eidx[EE + e];
    atomicMax(&lastE[s * NN + d], e);
}

// ---------------- (row, key-tile) bucketing of bias entries (layer-invariant)
__global__ __launch_bounds__(256) void rt_count(const int* __restrict__ eidx,
                                                const int* __restrict__ lastE,
                                                int* __restrict__ cnt2) {
    int e = blockIdx.x * 256 + threadIdx.x;
    int s = eidx[e], d = eidx[EE + e];
    if (lastE[s * NN + d] == e) atomicAdd(&cnt2[s * NTILE_TOT + (d >> 6)], 1);
}

// single-block row prefix over cnt2 (row sums computed inline)
__global__ __launch_bounds__(256) void scan2048(const int* __restrict__ cnt2,
                                                int* __restrict__ rowptr) {
    __shared__ int sums[256];
    int t = threadIdx.x;
    int loc[8];
    int s = 0;
#pragma unroll
    for (int i = 0; i < 8; ++i) {
        loc[i] = s;
        int rs = 0;
        for (int k = 0; k < NTILE_TOT; ++k) rs += cnt2[(t * 8 + i) * NTILE_TOT + k];
        s += rs;
    }
    sums[t] = s;
    __syncthreads();
    for (int off = 1; off < 256; off <<= 1) {
        int v = (t >= off) ? sums[t - off] : 0;
        __syncthreads();
        sums[t] += v;
        __syncthreads();
    }
    int base = (t == 0) ? 0 : sums[t - 1];
#pragma unroll
    for (int i = 0; i < 8; ++i) rowptr[t * 8 + i] = base + loc[i];
    if (t == 255) rowptr[NN] = sums[255];
}

__global__ __launch_bounds__(256) void rt_scan(const int* __restrict__ rowptr,
                                               const int* __restrict__ cnt2,
                                               int* __restrict__ rtptr,
                                               int* __restrict__ rtoff) {
    int row = blockIdx.x * 256 + threadIdx.x;
    if (row >= NN) return;
    int base = rowptr[row];
#pragma unroll
    for (int t = 0; t < NTILE_TOT; ++t) {
        rtptr[row * NTILE_TOT + t] = base;
        rtoff[row * NTILE_TOT + t] = base;
        base += cnt2[row * NTILE_TOT + t];
    }
    if (row == NN - 1) rtptr[NN * NTILE_TOT] = base;
}

// fill buckets: dst stored relative to tile (0..63); bias pre-scaled by log2e
__global__ __launch_bounds__(256) void rt_fill(const int* __restrict__ eidx,
                                               const int* __restrict__ lastE,
                                               const float* __restrict__ eb,
                                               int* __restrict__ rtoff,
                                               int* __restrict__ csr_dst,
                                               float* __restrict__ csr_b) {
    int e = blockIdx.x * 256 + threadIdx.x;
    int s = eidx[e], d = eidx[EE + e];
    if (lastE[s * NN + d] == e) {
        int pos = atomicAdd(&rtoff[s * NTILE_TOT + (d >> 6)], 1);
        csr_dst[pos] = d & 63;
#pragma unroll
        for (int j = 0; j < 8; ++j) csr_b[(size_t)pos * 8 + j] = eb[(size_t)e * 8 + j] * LOG2E;
    }
}

// ---------------- split-K flash attention (round-12 structure, BIASLDS=1)
// grid 768 = qblk(32) x head(8) x ks(3), XCD-chunk swizzled. 1 barrier/tile.
__global__ __launch_bounds__(256) void attn_mfma(const ushort* __restrict__ qb,
                                                 const ushort* __restrict__ kb,
                                                 const ushort* __restrict__ vtb,
                                                 const int* __restrict__ rtptr,
                                                 const int* __restrict__ csr_dst,
                                                 const float* __restrict__ csr_b,
                                                 float* __restrict__ opart,
                                                 float* __restrict__ Mp,
                                                 float* __restrict__ Sp) {
    const int id = blockIdx.x;
    const int f = (id & 7) * 96 + (id >> 3);    // 768 blocks, 96/XCD
    const int n0 = (f & 31) * 64;
    const int head = (f >> 5) & 7;
    const int ks = f >> 8;                       // 0..2
    const int tstart = (ks * 32) / 3, tend = ((ks + 1) * 32) / 3;   // 10/11/11 tiles
    const int t = threadIdx.x;
    const int w = t >> 6, l = t & 63;
    const int lq = l & 15, lg = l >> 4;

    __shared__ __align__(16) ushort Ks2[2][64 * 64];   // K dbuf, swizzled
    __shared__ __align__(16) ushort Vs2[2][64 * 64];   // V dbuf, swizzled
    __shared__ __align__(16) ushort Bb[4][16 * 72];    // per-wave bias mini-tile (bf16)
    __shared__ int Rt[64][12];                         // bucket bounds per block row

    // persistent Q fragments (pre-scaled by QSCALE): rows n0 + w*16 + lq
    bf16x8 qf0, qf1;
    {
        int r = n0 + w * 16 + lq;
        const ushort* qp = qb + ((size_t)head * NN + r) * HD + lg * 8;
        qf0 = *(const bf16x8*)qp;
        qf1 = *(const bf16x8*)(qp + 32);
    }
    const int ntile = tend - tstart;
    for (int i = t; i < 64 * 12; i += 256) {
        int r = i / 12, c = i % 12;
        if (c <= ntile) Rt[r][c] = rtptr[(n0 + r) * NTILE_TOT + tstart + c];
    }
    float M = -1e30f, S = 0.f;
    f32x4 o[4];
#pragma unroll
    for (int db = 0; db < 4; ++db) o[db] = (f32x4){0.f, 0.f, 0.f, 0.f};

    auto stageK = [&](int buf, int tile) {
        int m0k = tile * 64;
#pragma unroll
        for (int s = 0; s < 2; ++s) {
            int slot = t + s * 256;
            int rr = slot >> 3, blk = slot & 7, sb = blk ^ (rr & 7);
            GLD16(kb + ((size_t)head * NN + m0k + rr) * 64 + sb * 8,
                  &Ks2[buf][rr * 64 + blk * 8]);
        }
    };
    auto stageV = [&](int buf, int tile) {
        int m0k = tile * 64;
#pragma unroll
        for (int s = 0; s < 2; ++s) {
            int slot = t + s * 256;
            int rr = slot >> 3, blk = slot & 7, sb = blk ^ (rr & 7);
            GLD16(vtb + ((size_t)head * 64 + rr) * NN + m0k + sb * 8,
                  &Vs2[buf][rr * 64 + blk * 8]);
        }
    };

    stageK(0, tstart);
    stageV(0, tstart);
    __syncthreads();   // tile 0 landed, Rt visible

    // P lane-exchange constants (dest lane lg pulls from src lane ((2lg+c)&3)*16+lq)
    const int sl0 = (((lg << 1) + 0) & 3) * 16 + lq;
    const int sl1 = (((lg << 1) + 1) & 3) * 16 + lq;
    const int hi = lg & 2;

    for (int tt = tstart; tt < tend; ++tt) {
        const int tl = tt - tstart;
        const int cb = tl & 1;
        if (tt + 1 < tend) { stageK(cb ^ 1, tt + 1); stageV(cb ^ 1, tt + 1); }

        const int rq = w * 16 + lq;
        const int p0 = Rt[rq][tl], p1 = Rt[rq][tl + 1];

        // zero this wave's bias mini-tile (wave-coherent, no barrier needed)
        for (int i = l; i < 144; i += 64)
            *(uint4*)&Bb[w][i * 8] = (uint4){0, 0, 0, 0};
        // scatter bucket entries (lg==0 lanes only; ~1 entry/row avg)
        if (lg == 0) {
            for (int e = p0; e < p1; ++e)
                Bb[w][lq * 72 + csr_dst[e]] = f2bf(csr_b[(size_t)e * 8 + head]);
        }

        // ---- QK^T (swapped): vv[b][j] = score[q=lq][key = b*16 + lg*4 + j]
        f32x4 vv[4];
        {
            const ushort* Kb_ = &Ks2[cb][0];
            __builtin_amdgcn_s_setprio(1);
#pragma unroll
            for (int b = 0; b < 4; ++b) {
                int key = b * 16 + lq;
                bf16x8 k0 = *(const bf16x8*)&Kb_[key * 64 + ((lg ^ (key & 7)) * 8)];
                bf16x8 k1 = *(const bf16x8*)&Kb_[key * 64 + (((lg + 4) ^ (key & 7)) * 8)];
                f32x4 s_ = {0.f, 0.f, 0.f, 0.f};
                s_ = __builtin_amdgcn_mfma_f32_16x16x32_bf16(k0, qf0, s_, 0, 0, 0);
                s_ = __builtin_amdgcn_mfma_f32_16x16x32_bf16(k1, qf1, s_, 0, 0, 0);
                vv[b] = s_;
            }
            __builtin_amdgcn_s_setprio(0);
        }

        // ---- bias merge from mini-tile
#pragma unroll
        for (int b = 0; b < 4; ++b) {
            uint2 bb = *(const uint2*)&Bb[w][lq * 72 + b * 16 + lg * 4];
            vv[b][0] += __builtin_bit_cast(float, bb.x << 16);
            vv[b][1] += __builtin_bit_cast(float, bb.x & 0xffff0000u);
            vv[b][2] += __builtin_bit_cast(float, bb.y << 16);
            vv[b][3] += __builtin_bit_cast(float, bb.y & 0xffff0000u);
        }

        // ---- wave-local online softmax (log2 space), exact defer-rescale
        float mx = vv[0][0];
#pragma unroll
        for (int b = 0; b < 4; ++b)
#pragma unroll
            for (int j = 0; j < 4; ++j) mx = fmaxf(mx, vv[b][j]);
        mx = fmaxf(mx, __shfl_xor(mx, 16, 64));
        mx = fmaxf(mx, __shfl_xor(mx, 32, 64));
        if (!__all(mx <= M)) {
            float Mn = fmaxf(M, mx);
            float fr = exp2f(M - Mn);
            M = Mn;
            S *= fr;
#pragma unroll
            for (int j = 0; j < 4; ++j) {
                float Fj = __shfl(fr, lg * 4 + j, 64);
                o[0][j] *= Fj; o[1][j] *= Fj; o[2][j] *= Fj; o[3][j] *= Fj;
            }
        }
        float ts = 0.f;
#pragma unroll
        for (int b = 0; b < 4; ++b)
#pragma unroll
            for (int j = 0; j < 4; ++j) { vv[b][j] = exp2f(vv[b][j] - M); ts += vv[b][j]; }
        ts += __shfl_xor(ts, 16, 64);
        ts += __shfl_xor(ts, 32, 64);
        S += ts;

        // ---- pack P: U[2b+p] = bf16pair(vv[b][2p], vv[b][2p+1]) via v_cvt_pk
        uint U0, U1, U2, U3, U4, U5, U6, U7;
        asm("v_cvt_pk_bf16_f32 %0, %1, %2" : "=v"(U0) : "v"(vv[0][0]), "v"(vv[0][1]));
        asm("v_cvt_pk_bf16_f32 %0, %1, %2" : "=v"(U1) : "v"(vv[0][2]), "v"(vv[0][3]));
        asm("v_cvt_pk_bf16_f32 %0, %1, %2" : "=v"(U2) : "v"(vv[1][0]), "v"(vv[1][1]));
        asm("v_cvt_pk_bf16_f32 %0, %1, %2" : "=v"(U3) : "v"(vv[1][2]), "v"(vv[1][3]));
        asm("v_cvt_pk_bf16_f32 %0, %1, %2" : "=v"(U4) : "v"(vv[2][0]), "v"(vv[2][1]));
        asm("v_cvt_pk_bf16_f32 %0, %1, %2" : "=v"(U5) : "v"(vv[2][2]), "v"(vv[2][3]));
        asm("v_cvt_pk_bf16_f32 %0, %1, %2" : "=v"(U6) : "v"(vv[3][0]), "v"(vv[3][1]));
        asm("v_cvt_pk_bf16_f32 %0, %1, %2" : "=v"(U7) : "v"(vv[3][2]), "v"(vv[3][3]));

        // ---- in-register P exchange: pa0 = P[lq][keys lg*8..+7], pa1 = keys 32+lg*8..+7
        uint ra, rb;
        ra = (uint)__shfl((int)U0, sl0); rb = (uint)__shfl((int)U2, sl0);
        uint p00 = hi ? rb : ra;
        ra = (uint)__shfl((int)U1, sl0); rb = (uint)__shfl((int)U3, sl0);
        uint p01 = hi ? rb : ra;
        ra = (uint)__shfl((int)U0, sl1); rb = (uint)__shfl((int)U2, sl1);
        uint p02 = hi ? rb : ra;
        ra = (uint)__shfl((int)U1, sl1); rb = (uint)__shfl((int)U3, sl1);
        uint p03 = hi ? rb : ra;
        ra = (uint)__shfl((int)U4, sl0); rb = (uint)__shfl((int)U6, sl0);
        uint p10 = hi ? rb : ra;
        ra = (uint)__shfl((int)U5, sl0); rb = (uint)__shfl((int)U7, sl0);
        uint p11 = hi ? rb : ra;
        ra = (uint)__shfl((int)U4, sl1); rb = (uint)__shfl((int)U6, sl1);
        uint p12 = hi ? rb : ra;
        ra = (uint)__shfl((int)U5, sl1); rb = (uint)__shfl((int)U7, sl1);
        uint p13 = hi ? rb : ra;
        uint4 pu0 = {p00, p01, p02, p03};
        uint4 pu1 = {p10, p11, p12, p13};
        bf16x8 pa0 = __builtin_bit_cast(bf16x8, pu0);
        bf16x8 pa1 = __builtin_bit_cast(bf16x8, pu1);

        // ---- PV: A = P (in-register), B = V^T from LDS
        {
            const ushort* Vb_ = &Vs2[cb][0];
            __builtin_amdgcn_s_setprio(1);
#pragma unroll
            for (int db = 0; db < 4; ++db) {
                int dim = db * 16 + lq;
                bf16x8 v0 = *(const bf16x8*)&Vb_[dim * 64 + ((lg ^ (dim & 7)) * 8)];
                bf16x8 v1 = *(const bf16x8*)&Vb_[dim * 64 + (((lg + 4) ^ (dim & 7)) * 8)];
                o[db] = __builtin_amdgcn_mfma_f32_16x16x32_bf16(pa0, v0, o[db], 0, 0, 0);
                o[db] = __builtin_amdgcn_mfma_f32_16x16x32_bf16(pa1, v1, o[db], 0, 0, 0);
            }
            __builtin_amdgcn_s_setprio(0);
        }
        __syncthreads();   // next-tile stage landed; buffers free for reuse
    }

    // ---- write partials: o[db][j] is row n0+w*16+lg*4+j, dim db*16+lq
#pragma unroll
    for (int db = 0; db < 4; ++db)
#pragma unroll
        for (int j = 0; j < 4; ++j) {
            int r = n0 + w * 16 + lg * 4 + j;
            opart[((size_t)ks * NN + r) * HH + head * HD + db * 16 + lq] = o[db][j];
        }
    if (l < 16) {
        int r = n0 + w * 16 + l;
        Mp[((size_t)ks * NHH + head) * NN + r] = M;
        Sp[((size_t)ks * NHH + head) * NN + r] = S;
    }
}

// combine 3 partials -> bf16 attention output (log2-space M)
__global__ __launch_bounds__(256) void attn_combine(const float* __restrict__ opart,
                                                    const float* __restrict__ Mp,
                                                    const float* __restrict__ Sp,
                                                    ushort* __restrict__ aob) {
    int i = blockIdx.x * 256 + threadIdx.x;
    int row = i >> 9, col = i & 511;
    int head = col >> 6;
    float m0 = Mp[(size_t)head * NN + row];
    float m1 = Mp[((size_t)NHH + head) * NN + row];
    float m2 = Mp[((size_t)2 * NHH + head) * NN + row];
    float s0 = Sp[(size_t)head * NN + row];
    float s1 = Sp[((size_t)NHH + head) * NN + row];
    float s2 = Sp[((size_t)2 * NHH + head) * NN + row];
    float m = fmaxf(m0, fmaxf(m1, m2));
    float w0 = exp2f(m0 - m), w1 = exp2f(m1 - m), w2 = exp2f(m2 - m);
    float num = opart[(size_t)row * HH + col] * w0
              + opart[((size_t)NN + row) * HH + col] * w1
              + opart[((size_t)2 * NN + row) * HH + col] * w2;
    float den = s0 * w0 + s1 * w1 + s2 * w2;
    aob[i] = f2bf(num / den);
}

// ---------------- LayerNorm(out = LN(a + b) * g + be); optional bf16 copy
template<int BF16OUT>
__global__ __launch_bounds__(256) void ln_kernel(const float* __restrict__ a,
                                                 const float* __restrict__ b,
                                                 const float* __restrict__ g,
                                                 const float* __restrict__ be,
                                                 float* __restrict__ out,
                                                 ushort* __restrict__ outb) {
    int row = blockIdx.x * 4 + (threadIdx.x >> 6);
    int lane = threadIdx.x & 63;
    const float* pa = a + (size_t)row * HH;
    const float* pb = b + (size_t)row * HH;
    float x[8];
    float s = 0.f;
#pragma unroll
    for (int i = 0; i < 8; ++i) { x[i] = pa[lane + i * 64] + pb[lane + i * 64]; s += x[i]; }
#pragma unroll
    for (int off = 32; off > 0; off >>= 1) s += __shfl_xor(s, off, 64);
    float mean = s * (1.f / 512.f);
    float vs = 0.f;
#pragma unroll
    for (int i = 0; i < 8; ++i) { float d = x[i] - mean; vs += d * d; }
#pragma unroll
    for (int off = 32; off > 0; off >>= 1) vs += __shfl_xor(vs, off, 64);
    float rs = rsqrtf(vs * (1.f / 512.f) + 1e-5f);
    float* po = out + (size_t)row * HH;
    ushort* pob = outb + (size_t)row * HH;
#pragma unroll
    for (int i = 0; i < 8; ++i) {
        float v = (x[i] - mean) * rs * g[lane + i * 64] + be[lane + i * 64];
        po[lane + i * 64] = v;
        if (BF16OUT) pob[lane + i * 64] = f2bf(v);
    }
}

extern "C" void kernel_launch(void* const* d_in, const int* in_sizes, int n_in,
                              void* d_out, int out_size, void* d_ws, size_t ws_size,
                              hipStream_t stream) {
    const float* x   = (const float*)d_in[0];
    const int*  eidx = (const int*)d_in[1];
    const float* ea  = (const float*)d_in[2];
    const float* Wn = (const float*)d_in[3];  const float* bn = (const float*)d_in[4];
    const float* We = (const float*)d_in[5];  const float* be = (const float*)d_in[6];
    const float* Wq = (const float*)d_in[7];  const float* bq = (const float*)d_in[8];
    const float* Wk = (const float*)d_in[9];  const float* bk = (const float*)d_in[10];
    const float* Wv = (const float*)d_in[11]; const float* bv = (const float*)d_in[12];
    const float* Wo = (const float*)d_in[13]; const float* bo = (const float*)d_in[14];
    const float* W1 = (const float*)d_in[15]; const float* b1 = (const float*)d_in[16];
    const float* W2 = (const float*)d_in[17]; const float* b2 = (const float*)d_in[18];
    const float* g1 = (const float*)d_in[19]; const float* be1 = (const float*)d_in[20];
    const float* g2 = (const float*)d_in[21]; const float* be2 = (const float*)d_in[22];
    float* out = (float*)d_out;

    // workspace carve (bytes, 256-aligned)
    char* base = (char*)d_ws;
    size_t off = 0;
    auto carve = [&](size_t bytes) { void* p = base + off; off = (off + bytes + 255) & ~(size_t)255; return p; };
    float*  h    = (float*)carve((size_t)NN * HH * 4);
    ushort* hb   = (ushort*)carve((size_t)NN * HH * 2);
    // [po, ff1b, qb, kbf] contiguous 16 MB -> aliased as lastE during setup;
    // [po, ff1b] = 12 MB -> aliased as opart (3 x 4 MB) during attention
    float*  po   = (float*)carve((size_t)NN * HH * 4);
    ushort* ff1b = (ushort*)carve((size_t)NN * 4 * HH * 2);
    ushort* qb   = (ushort*)carve((size_t)NN * HH * 2);
    ushort* kbf  = (ushort*)carve((size_t)NN * HH * 2);
    ushort* vtb  = (ushort*)carve((size_t)NN * HH * 2);
    ushort* aob  = (ushort*)carve((size_t)NN * HH * 2);
    ushort* xb   = (ushort*)carve((size_t)NN * NF_ * 2);
    ushort* WnT  = (ushort*)carve((size_t)HH * NF_ * 2);
    ushort* WqkvT= (ushort*)carve((size_t)3 * HH * HH * 2);
    ushort* WoT  = (ushort*)carve((size_t)HH * HH * 2);
    ushort* W1T  = (ushort*)carve((size_t)4 * HH * HH * 2);
    ushort* W2T  = (ushort*)carve((size_t)4 * HH * HH * 2);
    float*  bqkv = (float*)carve((size_t)3 * HH * 4);
    float*  eb   = (float*)carve((size_t)EE * NHH * 4);
    float*  csr_b= (float*)carve((size_t)EE * NHH * 4);
    float*  Mp   = (float*)carve((size_t)KSPLIT * NHH * NN * 4);
    float*  Sp   = (float*)carve((size_t)KSPLIT * NHH * NN * 4);
    int* rowptr  = (int*)carve((size_t)(NN + 1) * 4);
    int* csr_dst = (int*)carve((size_t)EE * 4);
    int* cnt2    = (int*)carve((size_t)NN * NTILE_TOT * 4);
    int* rtptr   = (int*)carve((size_t)(NN * NTILE_TOT + 1) * 4);
    int* rtoff   = (int*)carve((size_t)NN * NTILE_TOT * 4);
    int* lastE = (int*)po;            // setup alias (po+ff1b+qb+kbf = 16 MB)
    float* opart = (float*)po;        // attention partials alias po+ff1b (12 MB)

    // ---- setup
    hipMemsetAsync(lastE, 0xFF, (size_t)NN * NN * 4, stream);
    hipMemsetAsync(cnt2, 0, (size_t)NN * NTILE_TOT * 4, stream);

    setup_misc<<<1281, 256, 0, stream>>>(ea, We, be, eb, x, xb, bq, bk, bv, bqkv);
    wtrans_all<<<3136, 256, 0, stream>>>(Wn, Wq, Wk, Wv, Wo, W1, W2,
                                         WnT, WqkvT, WoT, W1T, W2T);
    amax_kernel<<<EE / 256, 256, 0, stream>>>(eidx, lastE);
    rt_count<<<EE / 256, 256, 0, stream>>>(eidx, lastE, cnt2);
    scan2048<<<1, 256, 0, stream>>>(cnt2, rowptr);
    rt_scan<<<NN / 256, 256, 0, stream>>>(rowptr, cnt2, rtptr, rtoff);
    rt_fill<<<EE / 256, 256, 0, stream>>>(eidx, lastE, eb, rtoff, csr_dst, csr_b);

    // h = x @ Wn + bn  (f32 + bf16)
    gemm_mfma<64, 64, 1, 0><<<dim3(HH / 64, NN / 64), 256, 0, stream>>>(
        xb, WnT, bn, h, hb, nullptr, nullptr, nullptr, NN, HH, NF_);

    // ---- transformer layers (uniform BN=64)
    for (int d = 0; d < DEPTH; ++d) {
        gemm_mfma<64, 64, 3, 0><<<dim3(3 * HH / 64, NN / 64), 256, 0, stream>>>(
            hb, WqkvT, bqkv, nullptr, nullptr, qb, kbf, vtb, NN, 3 * HH, HH);
        attn_mfma<<<dim3(32 * NHH * KSPLIT), 256, 0, stream>>>(
            qb, kbf, vtb, rtptr, csr_dst, csr_b, opart, Mp, Sp);
        attn_combine<<<NN * HH / 256, 256, 0, stream>>>(opart, Mp, Sp, aob);
        gemm_mfma<32, 64, 0, 0><<<dim3(HH / 64, NN / 32), 256, 0, stream>>>(
            aob, WoT, bo, po, nullptr, nullptr, nullptr, nullptr, NN, HH, HH);
        ln_kernel<1><<<NN / 4, 256, 0, stream>>>(h, po, g1, be1, h, hb);
        gemm_mfma<64, 64, 2, 1><<<dim3(4 * HH / 64, NN / 64), 256, 0, stream>>>(
            hb, W1T, b1, nullptr, ff1b, nullptr, nullptr, nullptr, NN, 4 * HH, HH);
        gemm_mfma<32, 64, 0, 0><<<dim3(HH / 64, NN / 32), 256, 0, stream>>>(
            ff1b, W2T, b2, po, nullptr, nullptr, nullptr, nullptr, NN, HH, 4 * HH);
        float* dst = (d == DEPTH - 1) ? out : h;
        ln_kernel<1><<<NN / 4, 256, 0, stream>>>(h, po, g2, be2, dst, hb);
    }
    (void)in_sizes; (void)n_in; (void)out_size; (void)ws_size;
}